// Round 1
// baseline (7998.796 us; speedup 1.0000x reference)
//
#include <hip/hip_runtime.h>
#include <hip/hip_bf16.h>
#include <math.h>

// ---- problem constants ----
#define Bsz   32
#define Ssz   512
#define Fsz   40
#define Dsz   512
#define Hh    8
#define Lnum  4
#define Tsz   513           // S + 1 (cls token)
#define DKsz  256
#define DVsz  512
#define HKsz  32
#define HVsz  64
#define Msz   (Bsz*Tsz)     // 16416 rows
#define MLPsz 2048

__device__ __forceinline__ float wave_sum(float v) {
#pragma unroll
  for (int off = 32; off > 0; off >>= 1) v += __shfl_xor(v, off, 64);
  return v;
}

// ---- positional encoding table (T x D) ----
__global__ void pos_kernel(float* __restrict__ pos) {
  int idx = blockIdx.x * 256 + threadIdx.x;
  if (idx >= Tsz * Dsz) return;
  int t = idx / Dsz, d = idx % Dsz;
  float e = (float)(2 * (d >> 1)) / (float)Dsz;
  float den = powf(10000.f, e);
  float a = (float)t / den;
  pos[idx] = (d & 1) ? cosf(a) : sinf(a);
}

// ---- BiN temporal stats: per (b,f) mean + 1/std over S (ddof=1) ----
__global__ void tstat_kernel(const float* __restrict__ x,
                             float* __restrict__ mt, float* __restrict__ rst) {
  int bf = blockIdx.x;               // 0..B*F-1
  int b = bf / Fsz, f = bf % Fsz;
  int lane = threadIdx.x;
  const float* xp = x + (size_t)b * Ssz * Fsz + f;
  float s = 0.f, sq = 0.f;
  for (int i = lane; i < Ssz; i += 64) {
    float v = xp[(size_t)i * Fsz];
    s += v; sq += v * v;
  }
  s = wave_sum(s); sq = wave_sum(sq);
  if (lane == 0) {
    float m = s / (float)Ssz;
    float var = (sq - (float)Ssz * m * m) / (float)(Ssz - 1);
    float st = sqrtf(fmaxf(var, 0.f));
    if (st < 1e-4f) st = 1.f;
    mt[bf] = m;
    rst[bf] = 1.f / st;
  }
}

// ---- BiN feature-norm + combine + embedding GEMM + cls + pos ----
__global__ __launch_bounds__(64) void embed_kernel(
    const float* __restrict__ x, const float* __restrict__ l1,
    const float* __restrict__ b1, const float* __restrict__ l2,
    const float* __restrict__ b2, const float* __restrict__ y1p,
    const float* __restrict__ y2p, const float* __restrict__ emb_w,
    const float* __restrict__ emb_b, const float* __restrict__ cls,
    const float* __restrict__ pos, const float* __restrict__ mt,
    const float* __restrict__ rst, float* __restrict__ h) {
  int bx = blockIdx.x;               // 0..B*T-1
  int b = bx / Tsz, t = bx % Tsz;
  int lane = threadIdx.x;
  float* hp = h + (size_t)bx * Dsz;
  const float* pp = pos + (size_t)t * Dsz;
  if (t == Ssz) {                    // cls row
#pragma unroll
    for (int j = 0; j < 8; ++j) { int d = lane + j * 64; hp[d] = cls[d] + pp[d]; }
    return;
  }
  __shared__ float svec[64];
  float xv = 0.f;
  const float* xp = x + ((size_t)b * Ssz + t) * Fsz;
  if (lane < Fsz) xv = xp[lane];
  float s  = wave_sum(lane < Fsz ? xv : 0.f);
  float sq = wave_sum(lane < Fsz ? xv * xv : 0.f);
  float m = s / (float)Fsz;
  float var = (sq - (float)Fsz * m * m) / (float)(Fsz - 1);
  float sf = sqrtf(fmaxf(var, 0.f));
  if (sf < 1e-4f) sf = 1.f;
  float vec = 0.f;
  if (lane < Fsz) {
    float y1 = y1p[0], y2 = y2p[0];
    float z1 = (xv - m) / sf;
    float X1 = l1[t] * z1 + b1[t];
    int bf = b * Fsz + lane;
    float z2 = (xv - mt[bf]) * rst[bf];
    float X2 = l2[lane] * z2 + b2[lane];
    vec = y1 * X1 + y2 * X2;
  }
  svec[lane] = vec;
  __syncthreads();
#pragma unroll
  for (int j = 0; j < 8; ++j) {
    int d = lane + j * 64;
    float acc = emb_b[d] + pp[d];
    for (int f = 0; f < Fsz; ++f) acc += svec[f] * emb_w[f * Dsz + d];
    hp[d] = acc;
  }
}

// ---- LayerNorm over D=512 (biased var, eps 1e-5) ----
__global__ __launch_bounds__(64) void ln_kernel(
    const float* __restrict__ in, const float* __restrict__ w,
    const float* __restrict__ b, float* __restrict__ out) {
  int row = blockIdx.x, lane = threadIdx.x;
  const float* p = in + (size_t)row * Dsz;
  float4 v0 = *(const float4*)(p + lane * 4);
  float4 v1 = *(const float4*)(p + lane * 4 + 256);
  float s  = v0.x + v0.y + v0.z + v0.w + v1.x + v1.y + v1.z + v1.w;
  float sq = v0.x*v0.x + v0.y*v0.y + v0.z*v0.z + v0.w*v0.w
           + v1.x*v1.x + v1.y*v1.y + v1.z*v1.z + v1.w*v1.w;
  s = wave_sum(s); sq = wave_sum(sq);
  float m = s * (1.f / Dsz);
  float var = sq * (1.f / Dsz) - m * m;
  float r = rsqrtf(var + 1e-5f);
  float4 w0 = *(const float4*)(w + lane * 4);
  float4 w1 = *(const float4*)(w + lane * 4 + 256);
  float4 b0 = *(const float4*)(b + lane * 4);
  float4 b1v = *(const float4*)(b + lane * 4 + 256);
  float4 o0, o1;
  o0.x = (v0.x - m) * r * w0.x + b0.x;  o0.y = (v0.y - m) * r * w0.y + b0.y;
  o0.z = (v0.z - m) * r * w0.z + b0.z;  o0.w = (v0.w - m) * r * w0.w + b0.w;
  o1.x = (v1.x - m) * r * w1.x + b1v.x; o1.y = (v1.y - m) * r * w1.y + b1v.y;
  o1.z = (v1.z - m) * r * w1.z + b1v.z; o1.w = (v1.w - m) * r * w1.w + b1v.w;
  float* op = out + (size_t)row * Dsz;
  *(float4*)(op + lane * 4) = o0;
  *(float4*)(op + lane * 4 + 256) = o1;
}

// ---- generic fp32 GEMM: C[M,N] = act(A[M,K] @ W[K,N] + bias) + resid ----
// act: 0 none, 1 exact gelu
__global__ __launch_bounds__(256) void gemm_kernel(
    const float* __restrict__ A, const float* __restrict__ W,
    float* __restrict__ C, const float* __restrict__ bias,
    const float* __restrict__ resid, int M, int N, int K, int act) {
  __shared__ __align__(16) float As[32][68];
  __shared__ __align__(16) float Bs[32][68];
  int tid = threadIdx.x;
  int tx = tid & 15, ty = tid >> 4;
  int m0 = blockIdx.x * 64, n0 = blockIdx.y * 64;
  float acc[4][4] = {};
  for (int kt = 0; kt < K; kt += 32) {
#pragma unroll
    for (int l = 0; l < 2; ++l) {          // A tile 64x32 (store transposed)
      int idx = tid + l * 256;
      int ml = idx >> 3, k4 = (idx & 7) * 4;
      float4 a = make_float4(0.f, 0.f, 0.f, 0.f);
      int gm = m0 + ml;
      if (gm < M) a = *(const float4*)(A + (size_t)gm * K + kt + k4);
      As[k4 + 0][ml] = a.x; As[k4 + 1][ml] = a.y;
      As[k4 + 2][ml] = a.z; As[k4 + 3][ml] = a.w;
    }
#pragma unroll
    for (int l = 0; l < 2; ++l) {          // B tile 32x64
      int idx = tid + l * 256;
      int kk = idx >> 4, n4 = (idx & 15) * 4;
      float4 bv = make_float4(0.f, 0.f, 0.f, 0.f);
      int gn = n0 + n4;
      if (gn < N) bv = *(const float4*)(W + (size_t)(kt + kk) * N + gn);
      *(float4*)&Bs[kk][n4] = bv;
    }
    __syncthreads();
#pragma unroll
    for (int kk = 0; kk < 32; ++kk) {
      float4 a = *(const float4*)&As[kk][ty * 4];
      float4 b = *(const float4*)&Bs[kk][tx * 4];
      float av[4] = {a.x, a.y, a.z, a.w};
      float bv[4] = {b.x, b.y, b.z, b.w};
#pragma unroll
      for (int i = 0; i < 4; ++i)
#pragma unroll
        for (int j = 0; j < 4; ++j) acc[i][j] += av[i] * bv[j];
    }
    __syncthreads();
  }
#pragma unroll
  for (int i = 0; i < 4; ++i) {
    int gm = m0 + ty * 4 + i;
    if (gm >= M) continue;
#pragma unroll
    for (int j = 0; j < 4; ++j) {
      int gn = n0 + tx * 4 + j;
      if (gn >= N) continue;
      float v = acc[i][j];
      if (bias) v += bias[gn];
      if (act == 1) v = 0.5f * v * (1.f + erff(v * 0.70710678118654752f));
      if (resid) v += resid[(size_t)gm * N + gn];
      C[(size_t)gm * N + gn] = v;
    }
  }
}

// ---- gk low-rank part 2: gke = exp(log_sigmoid(gk1 @ w2 + b2)/16) ----
__global__ __launch_bounds__(256) void gk2_kernel(
    const float* __restrict__ gk1, const float* __restrict__ w2,
    const float* __restrict__ b2, float* __restrict__ gke) {
  int m = blockIdx.x, n = threadIdx.x;   // 256 threads = DK cols
  __shared__ float row[16];
  if (n < 16) row[n] = gk1[(size_t)m * 16 + n];
  __syncthreads();
  float acc = b2[n];
#pragma unroll
  for (int kk = 0; kk < 16; ++kk) acc += row[kk] * w2[kk * 256 + n];
  float z = acc;
  float ls = (z >= 0.f) ? -log1pf(expf(-z)) : z - log1pf(expf(z));
  gke[(size_t)m * 256 + n] = expf(ls * 0.0625f);
}

// ---- GLA recurrent scan, one block per (b,h), 64 lanes own v-columns ----
__global__ __launch_bounds__(64) void scan_kernel(
    const float* __restrict__ q, const float* __restrict__ k,
    const float* __restrict__ v, const float* __restrict__ g,
    const float* __restrict__ gke, const float* __restrict__ gnw,
    float* __restrict__ att) {
  int bh = blockIdx.x;
  int b = bh >> 3, hh = bh & 7;
  int lane = threadIdx.x;
  __shared__ __align__(16) float sq[32][32], sk[32][32], sg[32][32];
  __shared__ __align__(16) float sv[32][64], sgt[32][64];
  float S[32];
#pragma unroll
  for (int i = 0; i < 32; ++i) S[i] = 0.f;
  float gn = gnw[lane];
  const size_t qbase = (size_t)b * Tsz * DKsz + hh * HKsz;
  const size_t vbase = (size_t)b * Tsz * DVsz + hh * HVsz;
  for (int t0 = 0; t0 < Tsz; t0 += 32) {
    int steps = min(32, Tsz - t0);
    __syncthreads();
    for (int idx = lane; idx < steps * 8; idx += 64) {
      int t = idx >> 3, f = (idx & 7) * 4;
      size_t off = qbase + (size_t)(t0 + t) * DKsz + f;
      *(float4*)&sq[t][f] = *(const float4*)(q + off);
      *(float4*)&sk[t][f] = *(const float4*)(k + off);
      *(float4*)&sg[t][f] = *(const float4*)(gke + off);
    }
    for (int idx = lane; idx < steps * 16; idx += 64) {
      int t = idx >> 4, f = (idx & 15) * 4;
      size_t off = vbase + (size_t)(t0 + t) * DVsz + f;
      *(float4*)&sv[t][f]  = *(const float4*)(v + off);
      *(float4*)&sgt[t][f] = *(const float4*)(g + off);
    }
    __syncthreads();
    for (int t = 0; t < steps; ++t) {
      float vv = sv[t][lane];
      float o0 = 0.f, o1 = 0.f, o2 = 0.f, o3 = 0.f;
#pragma unroll
      for (int kk = 0; kk < 32; kk += 4) {
        float4 gg = *(const float4*)&sg[t][kk];
        float4 k4 = *(const float4*)&sk[t][kk];
        float4 qq = *(const float4*)&sq[t][kk];
        S[kk + 0] = S[kk + 0] * gg.x + k4.x * vv;  o0 += qq.x * S[kk + 0];
        S[kk + 1] = S[kk + 1] * gg.y + k4.y * vv;  o1 += qq.y * S[kk + 1];
        S[kk + 2] = S[kk + 2] * gg.z + k4.z * vv;  o2 += qq.z * S[kk + 2];
        S[kk + 3] = S[kk + 3] * gg.w + k4.w * vv;  o3 += qq.w * S[kk + 3];
      }
      float o = ((o0 + o1) + (o2 + o3)) * 0.17677669529663689f;  // 32^-0.5
      float ss = wave_sum(o * o);
      float r = rsqrtf(ss * (1.f / 64.f) + 1e-5f);
      float gv = sgt[t][lane];
      float sig = 1.f / (1.f + expf(-gv));
      att[vbase + (size_t)(t0 + t) * DVsz + lane] = o * r * gn * gv * sig;
    }
  }
}

// ---- final head: out[b, :3] = h[b, T-1, :] @ head_w + head_b ----
__global__ __launch_bounds__(64) void head_kernel(
    const float* __restrict__ h, const float* __restrict__ hw,
    const float* __restrict__ hb, float* __restrict__ out) {
  int b = blockIdx.x, lane = threadIdx.x;
  const float* p = h + ((size_t)b * Tsz + Ssz) * Dsz;
  float p0 = 0.f, p1 = 0.f, p2 = 0.f;
#pragma unroll
  for (int j = 0; j < 8; ++j) {
    int d = lane + j * 64;
    float hv = p[d];
    p0 += hv * hw[d * 3 + 0];
    p1 += hv * hw[d * 3 + 1];
    p2 += hv * hw[d * 3 + 2];
  }
  p0 = wave_sum(p0); p1 = wave_sum(p1); p2 = wave_sum(p2);
  if (lane == 0) {
    out[b * 3 + 0] = p0 + hb[0];
    out[b * 3 + 1] = p1 + hb[1];
    out[b * 3 + 2] = p2 + hb[2];
  }
}

extern "C" void kernel_launch(void* const* d_in, const int* in_sizes, int n_in,
                              void* d_out, int out_size, void* d_ws, size_t ws_size,
                              hipStream_t stream) {
  const float* x       = (const float*)d_in[0];
  const float* bin_l1  = (const float*)d_in[1];
  const float* bin_b1  = (const float*)d_in[2];
  const float* bin_l2  = (const float*)d_in[3];
  const float* bin_b2  = (const float*)d_in[4];
  const float* bin_y1  = (const float*)d_in[5];
  const float* bin_y2  = (const float*)d_in[6];
  const float* emb_w   = (const float*)d_in[7];
  const float* emb_b   = (const float*)d_in[8];
  const float* cls     = (const float*)d_in[9];
  const float* ln1_w   = (const float*)d_in[10];
  const float* ln1_b   = (const float*)d_in[11];
  const float* q_w     = (const float*)d_in[12];
  const float* k_w     = (const float*)d_in[13];
  const float* v_w     = (const float*)d_in[14];
  const float* g_w     = (const float*)d_in[15];
  const float* gk_w1   = (const float*)d_in[16];
  const float* gk_w2   = (const float*)d_in[17];
  const float* gk_b2   = (const float*)d_in[18];
  const float* gnorm_w = (const float*)d_in[19];
  const float* o_w     = (const float*)d_in[20];
  const float* ln2_w   = (const float*)d_in[21];
  const float* ln2_b   = (const float*)d_in[22];
  const float* mlp_w1  = (const float*)d_in[23];
  const float* mlp_b1  = (const float*)d_in[24];
  const float* mlp_w2  = (const float*)d_in[25];
  const float* mlp_b2  = (const float*)d_in[26];
  const float* head_w  = (const float*)d_in[27];
  const float* head_b  = (const float*)d_in[28];
  float* out = (float*)d_out;

  // workspace layout (floats); total ~50.96 M floats = ~194.4 MiB
  float* ws   = (float*)d_ws;
  float* pos  = ws;                                  // 262656
  float* h    = pos + (size_t)Tsz * Dsz;             // 8404992
  float* xn   = h + (size_t)Msz * Dsz;               // 8404992 (also att / xn2)
  float* shrd = xn + (size_t)Msz * Dsz;              // 33619968 (q..g | mlp mid)
  float* qb   = shrd;                                // 16416*256
  float* kb   = qb  + (size_t)Msz * DKsz;
  float* gkeb = kb  + (size_t)Msz * DKsz;
  float* vb   = gkeb+ (size_t)Msz * DKsz;
  float* gb   = vb  + (size_t)Msz * DVsz;
  float* mid  = shrd;                                // aliases q..g (dead by MLP)
  float* gk1b = shrd + (size_t)Msz * MLPsz;          // 262656
  float* mt   = gk1b + (size_t)Msz * 16;             // 1280
  float* rst  = mt + Bsz * Fsz;                      // 1280
  float* att  = xn;

  // ---- pre ----
  hipLaunchKernelGGL(pos_kernel, dim3((Tsz * Dsz + 255) / 256), dim3(256), 0, stream, pos);
  hipLaunchKernelGGL(tstat_kernel, dim3(Bsz * Fsz), dim3(64), 0, stream, x, mt, rst);
  hipLaunchKernelGGL(embed_kernel, dim3(Msz), dim3(64), 0, stream,
                     x, bin_l1, bin_b1, bin_l2, bin_b2, bin_y1, bin_y2,
                     emb_w, emb_b, cls, pos, mt, rst, h);

  dim3 blk256(256);
  for (int l = 0; l < Lnum; ++l) {
    const float* lw1 = ln1_w + l * Dsz;  const float* lb1 = ln1_b + l * Dsz;
    const float* qw  = q_w  + (size_t)l * Dsz * DKsz;
    const float* kw  = k_w  + (size_t)l * Dsz * DKsz;
    const float* vw  = v_w  + (size_t)l * Dsz * DVsz;
    const float* gw  = g_w  + (size_t)l * Dsz * DVsz;
    const float* g1w = gk_w1 + (size_t)l * Dsz * 16;
    const float* g2w = gk_w2 + (size_t)l * 16 * DKsz;
    const float* g2b = gk_b2 + (size_t)l * DKsz;
    const float* gnw = gnorm_w + l * HVsz;
    const float* ow  = o_w  + (size_t)l * DVsz * Dsz;
    const float* lw2 = ln2_w + l * Dsz;  const float* lb2 = ln2_b + l * Dsz;
    const float* m1w = mlp_w1 + (size_t)l * Dsz * MLPsz;
    const float* m1b = mlp_b1 + (size_t)l * MLPsz;
    const float* m2w = mlp_w2 + (size_t)l * MLPsz * Dsz;
    const float* m2b = mlp_b2 + (size_t)l * Dsz;

    hipLaunchKernelGGL(ln_kernel, dim3(Msz), dim3(64), 0, stream, h, lw1, lb1, xn);

    hipLaunchKernelGGL(gemm_kernel, dim3(257, DKsz / 64), blk256, 0, stream,
                       xn, qw, qb, (const float*)nullptr, (const float*)nullptr,
                       Msz, DKsz, Dsz, 0);
    hipLaunchKernelGGL(gemm_kernel, dim3(257, DKsz / 64), blk256, 0, stream,
                       xn, kw, kb, (const float*)nullptr, (const float*)nullptr,
                       Msz, DKsz, Dsz, 0);
    hipLaunchKernelGGL(gemm_kernel, dim3(257, DVsz / 64), blk256, 0, stream,
                       xn, vw, vb, (const float*)nullptr, (const float*)nullptr,
                       Msz, DVsz, Dsz, 0);
    hipLaunchKernelGGL(gemm_kernel, dim3(257, DVsz / 64), blk256, 0, stream,
                       xn, gw, gb, (const float*)nullptr, (const float*)nullptr,
                       Msz, DVsz, Dsz, 0);
    hipLaunchKernelGGL(gemm_kernel, dim3(257, 1), blk256, 0, stream,
                       xn, g1w, gk1b, (const float*)nullptr, (const float*)nullptr,
                       Msz, 16, Dsz, 0);
    hipLaunchKernelGGL(gk2_kernel, dim3(Msz), blk256, 0, stream, gk1b, g2w, g2b, gkeb);

    hipLaunchKernelGGL(scan_kernel, dim3(Bsz * Hh), dim3(64), 0, stream,
                       qb, kb, vb, gb, gkeb, gnw, att);

    // h = h + att @ o_w
    hipLaunchKernelGGL(gemm_kernel, dim3(257, Dsz / 64), blk256, 0, stream,
                       att, ow, h, (const float*)nullptr, h, Msz, Dsz, DVsz, 0);

    hipLaunchKernelGGL(ln_kernel, dim3(Msz), dim3(64), 0, stream, h, lw2, lb2, xn);
    // mid = gelu(xn @ w1 + b1)
    hipLaunchKernelGGL(gemm_kernel, dim3(257, MLPsz / 64), blk256, 0, stream,
                       xn, m1w, mid, m1b, (const float*)nullptr, Msz, MLPsz, Dsz, 1);
    // h = h + mid @ w2 + b2
    hipLaunchKernelGGL(gemm_kernel, dim3(257, Dsz / 64), blk256, 0, stream,
                       mid, m2w, h, m2b, h, Msz, Dsz, MLPsz, 0);
  }

  hipLaunchKernelGGL(head_kernel, dim3(Bsz), dim3(64), 0, stream, h, head_w, head_b, out);
}

// Round 2
// 3034.145 us; speedup vs baseline: 2.6363x; 2.6363x over previous
//
#include <hip/hip_runtime.h>
#include <hip/hip_bf16.h>
#include <math.h>

// ---- problem constants ----
#define Bsz   32
#define Ssz   512
#define Fsz   40
#define Dsz   512
#define Hh    8
#define Lnum  4
#define Tsz   513           // S + 1 (cls token)
#define DKsz  256
#define DVsz  512
#define HKsz  32
#define HVsz  64
#define Msz   (Bsz*Tsz)     // 16416 rows
#define Mpad  16512         // 129*128, padded row count for 128-tiles
#define MLPsz 2048

typedef __attribute__((ext_vector_type(4))) float f32x4;
typedef __attribute__((ext_vector_type(8))) short bf16x8;

__device__ __forceinline__ float bf2f(short s) {
  unsigned int u = ((unsigned int)(unsigned short)s) << 16;
  return __builtin_bit_cast(float, u);
}
__device__ __forceinline__ short f2bf(float f) {
  __hip_bfloat16 b = __float2bfloat16(f);
  return __builtin_bit_cast(short, b);
}

__device__ __forceinline__ float wave_sum(float v) {
#pragma unroll
  for (int off = 32; off > 0; off >>= 1) v += __shfl_xor(v, off, 64);
  return v;
}

// ---- positional encoding table (T x D) ----
__global__ void pos_kernel(float* __restrict__ pos) {
  int idx = blockIdx.x * 256 + threadIdx.x;
  if (idx >= Tsz * Dsz) return;
  int t = idx / Dsz, d = idx % Dsz;
  float e = (float)(2 * (d >> 1)) / (float)Dsz;
  float den = powf(10000.f, e);
  float a = (float)t / den;
  pos[idx] = (d & 1) ? cosf(a) : sinf(a);
}

// ---- BiN temporal stats: per (b,f) mean + 1/std over S (ddof=1) ----
__global__ void tstat_kernel(const float* __restrict__ x,
                             float* __restrict__ mt, float* __restrict__ rst) {
  int bf = blockIdx.x;
  int b = bf / Fsz, f = bf % Fsz;
  int lane = threadIdx.x;
  const float* xp = x + (size_t)b * Ssz * Fsz + f;
  float s = 0.f, sq = 0.f;
  for (int i = lane; i < Ssz; i += 64) {
    float v = xp[(size_t)i * Fsz];
    s += v; sq += v * v;
  }
  s = wave_sum(s); sq = wave_sum(sq);
  if (lane == 0) {
    float m = s / (float)Ssz;
    float var = (sq - (float)Ssz * m * m) / (float)(Ssz - 1);
    float st = sqrtf(fmaxf(var, 0.f));
    if (st < 1e-4f) st = 1.f;
    mt[bf] = m;
    rst[bf] = 1.f / st;
  }
}

// ---- BiN feature-norm + combine + embedding GEMM + cls + pos (fp32 out h) ----
__global__ __launch_bounds__(64) void embed_kernel(
    const float* __restrict__ x, const float* __restrict__ l1,
    const float* __restrict__ b1, const float* __restrict__ l2,
    const float* __restrict__ b2, const float* __restrict__ y1p,
    const float* __restrict__ y2p, const float* __restrict__ emb_w,
    const float* __restrict__ emb_b, const float* __restrict__ cls,
    const float* __restrict__ pos, const float* __restrict__ mt,
    const float* __restrict__ rst, float* __restrict__ h) {
  int bx = blockIdx.x;
  int b = bx / Tsz, t = bx % Tsz;
  int lane = threadIdx.x;
  float* hp = h + (size_t)bx * Dsz;
  const float* pp = pos + (size_t)t * Dsz;
  if (t == Ssz) {
#pragma unroll
    for (int j = 0; j < 8; ++j) { int d = lane + j * 64; hp[d] = cls[d] + pp[d]; }
    return;
  }
  __shared__ float svec[64];
  float xv = 0.f;
  const float* xp = x + ((size_t)b * Ssz + t) * Fsz;
  if (lane < Fsz) xv = xp[lane];
  float s  = wave_sum(lane < Fsz ? xv : 0.f);
  float sq = wave_sum(lane < Fsz ? xv * xv : 0.f);
  float m = s / (float)Fsz;
  float var = (sq - (float)Fsz * m * m) / (float)(Fsz - 1);
  float sf = sqrtf(fmaxf(var, 0.f));
  if (sf < 1e-4f) sf = 1.f;
  float vec = 0.f;
  if (lane < Fsz) {
    float y1 = y1p[0], y2 = y2p[0];
    float z1 = (xv - m) / sf;
    float X1 = l1[t] * z1 + b1[t];
    int bf = b * Fsz + lane;
    float z2 = (xv - mt[bf]) * rst[bf];
    float X2 = l2[lane] * z2 + b2[lane];
    vec = y1 * X1 + y2 * X2;
  }
  svec[lane] = vec;
  __syncthreads();
#pragma unroll
  for (int j = 0; j < 8; ++j) {
    int d = lane + j * 64;
    float acc = emb_b[d] + pp[d];
    for (int f = 0; f < Fsz; ++f) acc += svec[f] * emb_w[f * Dsz + d];
    hp[d] = acc;
  }
}

// ---- LayerNorm over D=512 (fp32 in, bf16 out) ----
__global__ __launch_bounds__(64) void ln_kernel(
    const float* __restrict__ in, const float* __restrict__ w,
    const float* __restrict__ b, short* __restrict__ out) {
  int row = blockIdx.x, lane = threadIdx.x;
  const float* p = in + (size_t)row * Dsz;
  float4 v0 = *(const float4*)(p + lane * 8);
  float4 v1 = *(const float4*)(p + lane * 8 + 4);
  float s  = v0.x + v0.y + v0.z + v0.w + v1.x + v1.y + v1.z + v1.w;
  float sq = v0.x*v0.x + v0.y*v0.y + v0.z*v0.z + v0.w*v0.w
           + v1.x*v1.x + v1.y*v1.y + v1.z*v1.z + v1.w*v1.w;
  s = wave_sum(s); sq = wave_sum(sq);
  float m = s * (1.f / Dsz);
  float var = sq * (1.f / Dsz) - m * m;
  float r = rsqrtf(var + 1e-5f);
  float4 w0 = *(const float4*)(w + lane * 8);
  float4 w1 = *(const float4*)(w + lane * 8 + 4);
  float4 b0 = *(const float4*)(b + lane * 8);
  float4 b1v = *(const float4*)(b + lane * 8 + 4);
  bf16x8 pk;
  pk[0] = f2bf((v0.x - m) * r * w0.x + b0.x);
  pk[1] = f2bf((v0.y - m) * r * w0.y + b0.y);
  pk[2] = f2bf((v0.z - m) * r * w0.z + b0.z);
  pk[3] = f2bf((v0.w - m) * r * w0.w + b0.w);
  pk[4] = f2bf((v1.x - m) * r * w1.x + b1v.x);
  pk[5] = f2bf((v1.y - m) * r * w1.y + b1v.y);
  pk[6] = f2bf((v1.z - m) * r * w1.z + b1v.z);
  pk[7] = f2bf((v1.w - m) * r * w1.w + b1v.w);
  *(bf16x8*)(out + (size_t)row * Dsz + lane * 8) = pk;
}

// ---- weight convert + transpose: Wt[n][k] = bf16(W[k][n]) ----
__global__ __launch_bounds__(256) void wt_kernel(const float* __restrict__ W,
    short* __restrict__ Wt, int K, int N) {
  __shared__ float t[32][33];
  int k0 = blockIdx.x * 32, n0 = blockIdx.y * 32;
  int tx = threadIdx.x & 31, ty = threadIdx.x >> 5;
#pragma unroll
  for (int r = 0; r < 32; r += 8)
    t[ty + r][tx] = W[(size_t)(k0 + ty + r) * N + n0 + tx];
  __syncthreads();
#pragma unroll
  for (int r = 0; r < 32; r += 8)
    Wt[(size_t)(n0 + ty + r) * K + k0 + tx] = f2bf(t[tx][ty + r]);
}

// ---- bf16 MFMA GEMM: C[Mpad,N] = act(A[Mpad,K]@Bt[N,K]^T + bias) + resid ----
// 128x128 tile, BK=32, 4 waves, 4x4 frags of 16x16x32. ACT: 0 none, 1 gelu.
// OBF: output bf16 (1) or fp32 (0).
template<int ACT, int OBF>
__global__ __launch_bounds__(256) void mgemm_kernel(
    const short* __restrict__ A, const short* __restrict__ Bt,
    void* __restrict__ Cv, const float* __restrict__ bias,
    const float* __restrict__ resid, int N, int K) {
  __shared__ short As[128 * 32];
  __shared__ short Bs[128 * 32];
  int tid = threadIdx.x;
  int lane = tid & 63, wid = tid >> 6;
  int wr = wid >> 1, wc = wid & 1;
  int m0 = blockIdx.x * 128, n0 = blockIdx.y * 128;
  f32x4 acc[4][4];
#pragma unroll
  for (int i = 0; i < 4; ++i)
#pragma unroll
    for (int j = 0; j < 4; ++j) acc[i][j] = (f32x4){0.f, 0.f, 0.f, 0.f};

  int kq = lane >> 4;          // k-quarter 0..3
  int rsel = lane & 15;

  for (int kt = 0; kt < K; kt += 32) {
    // stage 128x32 A-tile + B-tile, 16B granules, XOR-swizzled source (rule #21)
#pragma unroll
    for (int i = 0; i < 2; ++i) {
      int li = i * 256 + tid;                 // granule 0..511
      int row = li >> 2;
      int c8 = (li & 3) ^ (row & 3);
      const short* ga = A + (size_t)(m0 + row) * K + kt + c8 * 8;
      const short* gb = Bt + (size_t)(n0 + row) * K + kt + c8 * 8;
      int base = (i * 256 + wid * 64) * 8;    // wave-uniform LDS granule base
      __builtin_amdgcn_global_load_lds(
          (const __attribute__((address_space(1))) unsigned int*)ga,
          (__attribute__((address_space(3))) unsigned int*)&As[base], 16, 0, 0);
      __builtin_amdgcn_global_load_lds(
          (const __attribute__((address_space(1))) unsigned int*)gb,
          (__attribute__((address_space(3))) unsigned int*)&Bs[base], 16, 0, 0);
    }
    __syncthreads();
    bf16x8 af[4], bfr[4];
#pragma unroll
    for (int i = 0; i < 4; ++i) {
      int row = wr * 64 + i * 16 + rsel;
      int g = row * 4 + (kq ^ (row & 3));
      af[i] = *(const bf16x8*)&As[g * 8];
      int col = wc * 64 + i * 16 + rsel;
      int gB = col * 4 + (kq ^ (col & 3));
      bfr[i] = *(const bf16x8*)&Bs[gB * 8];
    }
#pragma unroll
    for (int i = 0; i < 4; ++i)
#pragma unroll
      for (int j = 0; j < 4; ++j)
        acc[i][j] = __builtin_amdgcn_mfma_f32_16x16x32_bf16(af[i], bfr[j], acc[i][j], 0, 0, 0);
    __syncthreads();
  }

#pragma unroll
  for (int i = 0; i < 4; ++i) {
    int rbase = m0 + wr * 64 + i * 16 + (lane >> 4) * 4;
#pragma unroll
    for (int j = 0; j < 4; ++j) {
      int gn = n0 + wc * 64 + j * 16 + (lane & 15);
      float bv = bias ? bias[gn] : 0.f;
#pragma unroll
      for (int r = 0; r < 4; ++r) {
        int gm = rbase + r;
        float v = acc[i][j][r] + bv;
        if (ACT == 1) v = 0.5f * v * (1.f + erff(v * 0.70710678118654752f));
        if (resid) v += resid[(size_t)gm * N + gn];
        if (OBF) ((short*)Cv)[(size_t)gm * N + gn] = f2bf(v);
        else     ((float*)Cv)[(size_t)gm * N + gn] = v;
      }
    }
  }
}

// ---- gk low-rank part 1: gk1[m,16] = xn[m,:] @ w1 (bf16 in, fp32 out) ----
__global__ __launch_bounds__(64) void gk1_kernel(const short* __restrict__ xn,
    const float* __restrict__ w1, float* __restrict__ gk1) {
  int m = blockIdx.x, lane = threadIdx.x;
  __shared__ float xr[512];
  bf16x8 v = *(const bf16x8*)(xn + (size_t)m * Dsz + lane * 8);
#pragma unroll
  for (int e = 0; e < 8; ++e) xr[lane * 8 + e] = bf2f(v[e]);
  __syncthreads();
  int c = lane & 15, q = lane >> 4;
  float acc = 0.f;
#pragma unroll 8
  for (int i = 0; i < 128; ++i) {
    int k = q * 128 + i;
    acc += xr[k] * w1[k * 16 + c];
  }
  acc += __shfl_xor(acc, 16, 64);
  acc += __shfl_xor(acc, 32, 64);
  if (lane < 16) gk1[(size_t)m * 16 + c] = acc;
}

// ---- gk low-rank part 2: gke = exp(log_sigmoid(gk1 @ w2 + b2)/16) ----
__global__ __launch_bounds__(256) void gk2_kernel(
    const float* __restrict__ gk1, const float* __restrict__ w2,
    const float* __restrict__ b2, float* __restrict__ gke) {
  int m = blockIdx.x, n = threadIdx.x;
  __shared__ float row[16];
  if (n < 16) row[n] = gk1[(size_t)m * 16 + n];
  __syncthreads();
  float acc = b2[n];
#pragma unroll
  for (int kk = 0; kk < 16; ++kk) acc += row[kk] * w2[kk * 256 + n];
  float z = acc;
  float ls = (z >= 0.f) ? -log1pf(expf(-z)) : z - log1pf(expf(z));
  gke[(size_t)m * 256 + n] = expf(ls * 0.0625f);
}

// ---- GLA recurrent scan (fp32 state), writes att in bf16 ----
__global__ __launch_bounds__(64) void scan_kernel(
    const float* __restrict__ q, const float* __restrict__ k,
    const float* __restrict__ v, const float* __restrict__ g,
    const float* __restrict__ gke, const float* __restrict__ gnw,
    short* __restrict__ att) {
  int bh = blockIdx.x;
  int b = bh >> 3, hh = bh & 7;
  int lane = threadIdx.x;
  __shared__ __align__(16) float sq[32][32], sk[32][32], sg[32][32];
  __shared__ __align__(16) float sv[32][64], sgt[32][64];
  float S[32];
#pragma unroll
  for (int i = 0; i < 32; ++i) S[i] = 0.f;
  float gn = gnw[lane];
  const size_t qbase = (size_t)b * Tsz * DKsz + hh * HKsz;
  const size_t vbase = (size_t)b * Tsz * DVsz + hh * HVsz;
  for (int t0 = 0; t0 < Tsz; t0 += 32) {
    int steps = min(32, Tsz - t0);
    __syncthreads();
    for (int idx = lane; idx < steps * 8; idx += 64) {
      int t = idx >> 3, f = (idx & 7) * 4;
      size_t off = qbase + (size_t)(t0 + t) * DKsz + f;
      *(float4*)&sq[t][f] = *(const float4*)(q + off);
      *(float4*)&sk[t][f] = *(const float4*)(k + off);
      *(float4*)&sg[t][f] = *(const float4*)(gke + off);
    }
    for (int idx = lane; idx < steps * 16; idx += 64) {
      int t = idx >> 4, f = (idx & 15) * 4;
      size_t off = vbase + (size_t)(t0 + t) * DVsz + f;
      *(float4*)&sv[t][f]  = *(const float4*)(v + off);
      *(float4*)&sgt[t][f] = *(const float4*)(g + off);
    }
    __syncthreads();
    for (int t = 0; t < steps; ++t) {
      float vv = sv[t][lane];
      float o0 = 0.f, o1 = 0.f, o2 = 0.f, o3 = 0.f;
#pragma unroll
      for (int kk = 0; kk < 32; kk += 4) {
        float4 gg = *(const float4*)&sg[t][kk];
        float4 k4 = *(const float4*)&sk[t][kk];
        float4 qq = *(const float4*)&sq[t][kk];
        S[kk + 0] = S[kk + 0] * gg.x + k4.x * vv;  o0 += qq.x * S[kk + 0];
        S[kk + 1] = S[kk + 1] * gg.y + k4.y * vv;  o1 += qq.y * S[kk + 1];
        S[kk + 2] = S[kk + 2] * gg.z + k4.z * vv;  o2 += qq.z * S[kk + 2];
        S[kk + 3] = S[kk + 3] * gg.w + k4.w * vv;  o3 += qq.w * S[kk + 3];
      }
      float o = ((o0 + o1) + (o2 + o3)) * 0.17677669529663689f;  // 32^-0.5
      float ss = wave_sum(o * o);
      float r = rsqrtf(ss * (1.f / 64.f) + 1e-5f);
      float gv = sgt[t][lane];
      float sig = 1.f / (1.f + expf(-gv));
      att[vbase + (size_t)(t0 + t) * DVsz + lane] = f2bf(o * r * gn * gv * sig);
    }
  }
}

// ---- final head ----
__global__ __launch_bounds__(64) void head_kernel(
    const float* __restrict__ h, const float* __restrict__ hw,
    const float* __restrict__ hb, float* __restrict__ out) {
  int b = blockIdx.x, lane = threadIdx.x;
  const float* p = h + ((size_t)b * Tsz + Ssz) * Dsz;
  float p0 = 0.f, p1 = 0.f, p2 = 0.f;
#pragma unroll
  for (int j = 0; j < 8; ++j) {
    int d = lane + j * 64;
    float hv = p[d];
    p0 += hv * hw[d * 3 + 0];
    p1 += hv * hw[d * 3 + 1];
    p2 += hv * hw[d * 3 + 2];
  }
  p0 = wave_sum(p0); p1 = wave_sum(p1); p2 = wave_sum(p2);
  if (lane == 0) {
    out[b * 3 + 0] = p0 + hb[0];
    out[b * 3 + 1] = p1 + hb[1];
    out[b * 3 + 2] = p2 + hb[2];
  }
}

extern "C" void kernel_launch(void* const* d_in, const int* in_sizes, int n_in,
                              void* d_out, int out_size, void* d_ws, size_t ws_size,
                              hipStream_t stream) {
  const float* x       = (const float*)d_in[0];
  const float* bin_l1  = (const float*)d_in[1];
  const float* bin_b1  = (const float*)d_in[2];
  const float* bin_l2  = (const float*)d_in[3];
  const float* bin_b2  = (const float*)d_in[4];
  const float* bin_y1  = (const float*)d_in[5];
  const float* bin_y2  = (const float*)d_in[6];
  const float* emb_w   = (const float*)d_in[7];
  const float* emb_b   = (const float*)d_in[8];
  const float* cls     = (const float*)d_in[9];
  const float* ln1_w   = (const float*)d_in[10];
  const float* ln1_b   = (const float*)d_in[11];
  const float* q_w     = (const float*)d_in[12];
  const float* k_w     = (const float*)d_in[13];
  const float* v_w     = (const float*)d_in[14];
  const float* g_w     = (const float*)d_in[15];
  const float* gk_w1   = (const float*)d_in[16];
  const float* gk_w2   = (const float*)d_in[17];
  const float* gk_b2   = (const float*)d_in[18];
  const float* gnorm_w = (const float*)d_in[19];
  const float* o_w     = (const float*)d_in[20];
  const float* ln2_w   = (const float*)d_in[21];
  const float* ln2_b   = (const float*)d_in[22];
  const float* mlp_w1  = (const float*)d_in[23];
  const float* mlp_b1  = (const float*)d_in[24];
  const float* mlp_w2  = (const float*)d_in[25];
  const float* mlp_b2  = (const float*)d_in[26];
  const float* head_w  = (const float*)d_in[27];
  const float* head_b  = (const float*)d_in[28];
  float* out = (float*)d_out;

  // ---- workspace layout (~196 MB) ----
  char* wptr = (char*)d_ws;
  auto alloc = [&](size_t bytes) { char* p = wptr; wptr += (bytes + 255) & ~(size_t)255; return p; };
  float* pos  = (float*)alloc((size_t)Tsz * Dsz * 4);
  float* h    = (float*)alloc((size_t)Mpad * Dsz * 4);
  short* xn   = (short*)alloc((size_t)Mpad * Dsz * 2);   // LN out; aliased as att
  float* qb   = (float*)alloc((size_t)Mpad * DKsz * 4);
  float* kb   = (float*)alloc((size_t)Mpad * DKsz * 4);
  float* gkeb = (float*)alloc((size_t)Mpad * DKsz * 4);
  float* vb   = (float*)alloc((size_t)Mpad * DVsz * 4);
  float* gb   = (float*)alloc((size_t)Mpad * DVsz * 4);
  float* gk1b = (float*)alloc((size_t)Mpad * 16 * 4);
  float* mt   = (float*)alloc((size_t)Bsz * Fsz * 4);
  float* rst  = (float*)alloc((size_t)Bsz * Fsz * 4);
  short* wtr  = (short*)alloc((size_t)12582912 * 2);     // transposed bf16 weights
  short* mid  = (short*)qb;      // MLP mid aliases q..g region (dead by then)
  short* att  = xn;              // scan output aliases xn (dead after gk1)

  // ---- weight convert+transpose (all layers) ----
  for (int l = 0; l < Lnum; ++l) {
    short* base = wtr + (size_t)l * 3145728;
    short* qwT = base;
    short* kwT = qwT + 131072;
    short* vwT = kwT + 131072;
    short* gwT = vwT + 262144;
    short* owT = gwT + 262144;
    short* m1T = owT + 262144;
    short* m2T = m1T + 1048576;
    hipLaunchKernelGGL(wt_kernel, dim3(16, 8),  dim3(256), 0, stream, q_w   + (size_t)l*Dsz*DKsz,   qwT, Dsz, DKsz);
    hipLaunchKernelGGL(wt_kernel, dim3(16, 8),  dim3(256), 0, stream, k_w   + (size_t)l*Dsz*DKsz,   kwT, Dsz, DKsz);
    hipLaunchKernelGGL(wt_kernel, dim3(16, 16), dim3(256), 0, stream, v_w   + (size_t)l*Dsz*DVsz,   vwT, Dsz, DVsz);
    hipLaunchKernelGGL(wt_kernel, dim3(16, 16), dim3(256), 0, stream, g_w   + (size_t)l*Dsz*DVsz,   gwT, Dsz, DVsz);
    hipLaunchKernelGGL(wt_kernel, dim3(16, 16), dim3(256), 0, stream, o_w   + (size_t)l*DVsz*Dsz,   owT, DVsz, Dsz);
    hipLaunchKernelGGL(wt_kernel, dim3(16, 64), dim3(256), 0, stream, mlp_w1+ (size_t)l*Dsz*MLPsz,  m1T, Dsz, MLPsz);
    hipLaunchKernelGGL(wt_kernel, dim3(64, 16), dim3(256), 0, stream, mlp_w2+ (size_t)l*MLPsz*Dsz,  m2T, MLPsz, Dsz);
  }

  // ---- pre ----
  hipLaunchKernelGGL(pos_kernel, dim3((Tsz * Dsz + 255) / 256), dim3(256), 0, stream, pos);
  hipLaunchKernelGGL(tstat_kernel, dim3(Bsz * Fsz), dim3(64), 0, stream, x, mt, rst);
  hipLaunchKernelGGL(embed_kernel, dim3(Msz), dim3(64), 0, stream,
                     x, bin_l1, bin_b1, bin_l2, bin_b2, bin_y1, bin_y2,
                     emb_w, emb_b, cls, pos, mt, rst, h);

  dim3 blk256(256);
  for (int l = 0; l < Lnum; ++l) {
    short* base = wtr + (size_t)l * 3145728;
    short* qwT = base;
    short* kwT = qwT + 131072;
    short* vwT = kwT + 131072;
    short* gwT = vwT + 262144;
    short* owT = gwT + 262144;
    short* m1T = owT + 262144;
    short* m2T = m1T + 1048576;
    const float* lw1 = ln1_w + l * Dsz;  const float* lb1 = ln1_b + l * Dsz;
    const float* g1w = gk_w1 + (size_t)l * Dsz * 16;
    const float* g2w = gk_w2 + (size_t)l * 16 * DKsz;
    const float* g2b = gk_b2 + (size_t)l * DKsz;
    const float* gnw = gnorm_w + l * HVsz;
    const float* lw2 = ln2_w + l * Dsz;  const float* lb2 = ln2_b + l * Dsz;
    const float* m1b = mlp_b1 + (size_t)l * MLPsz;
    const float* m2b = mlp_b2 + (size_t)l * Dsz;

    hipLaunchKernelGGL(ln_kernel, dim3(Msz), dim3(64), 0, stream, h, lw1, lb1, xn);

    hipLaunchKernelGGL((mgemm_kernel<0,0>), dim3(129, 2), blk256, 0, stream,
                       xn, qwT, (void*)qb, (const float*)nullptr, (const float*)nullptr, DKsz, Dsz);
    hipLaunchKernelGGL((mgemm_kernel<0,0>), dim3(129, 2), blk256, 0, stream,
                       xn, kwT, (void*)kb, (const float*)nullptr, (const float*)nullptr, DKsz, Dsz);
    hipLaunchKernelGGL((mgemm_kernel<0,0>), dim3(129, 4), blk256, 0, stream,
                       xn, vwT, (void*)vb, (const float*)nullptr, (const float*)nullptr, DVsz, Dsz);
    hipLaunchKernelGGL((mgemm_kernel<0,0>), dim3(129, 4), blk256, 0, stream,
                       xn, gwT, (void*)gb, (const float*)nullptr, (const float*)nullptr, DVsz, Dsz);
    hipLaunchKernelGGL(gk1_kernel, dim3(Msz), dim3(64), 0, stream, xn, g1w, gk1b);
    hipLaunchKernelGGL(gk2_kernel, dim3(Msz), blk256, 0, stream, gk1b, g2w, g2b, gkeb);

    hipLaunchKernelGGL(scan_kernel, dim3(Bsz * Hh), dim3(64), 0, stream,
                       qb, kb, vb, gb, gkeb, gnw, att);

    // h = h + att @ o_w
    hipLaunchKernelGGL((mgemm_kernel<0,0>), dim3(129, 4), blk256, 0, stream,
                       att, owT, (void*)h, (const float*)nullptr, h, Dsz, DVsz);

    hipLaunchKernelGGL(ln_kernel, dim3(Msz), dim3(64), 0, stream, h, lw2, lb2, xn);
    // mid = gelu(xn @ w1 + b1)   (bf16 out)
    hipLaunchKernelGGL((mgemm_kernel<1,1>), dim3(129, 16), blk256, 0, stream,
                       xn, m1T, (void*)mid, m1b, (const float*)nullptr, MLPsz, Dsz);
    // h = h + mid @ w2 + b2
    hipLaunchKernelGGL((mgemm_kernel<0,0>), dim3(129, 4), blk256, 0, stream,
                       mid, m2T, (void*)h, m2b, h, Dsz, MLPsz);
  }

  hipLaunchKernelGGL(head_kernel, dim3(Bsz), dim3(64), 0, stream, h, head_w, head_b, out);
}

// Round 3
// 2207.066 us; speedup vs baseline: 3.6242x; 1.3747x over previous
//
#include <hip/hip_runtime.h>
#include <hip/hip_bf16.h>
#include <math.h>

// ---- problem constants ----
#define Bsz   32
#define Ssz   512
#define Fsz   40
#define Dsz   512
#define Hh    8
#define Lnum  4
#define Tsz   513           // S + 1 (cls token)
#define DKsz  256
#define DVsz  512
#define HKsz  32
#define HVsz  64
#define Msz   (Bsz*Tsz)     // 16416 rows
#define Mpad  16512         // 129*128, padded row count for 128-tiles
#define MLPsz 2048
#define NCH   8             // scan chunks per (b,h)
#define CSZ   65            // chunk size (last chunk = 58)

typedef __attribute__((ext_vector_type(4))) float f32x4;
typedef __attribute__((ext_vector_type(8))) short bf16x8;

__device__ __forceinline__ float bf2f(short s) {
  unsigned int u = ((unsigned int)(unsigned short)s) << 16;
  return __builtin_bit_cast(float, u);
}
__device__ __forceinline__ short f2bf(float f) {
  __hip_bfloat16 b = __float2bfloat16(f);
  return __builtin_bit_cast(short, b);
}

__device__ __forceinline__ float wave_sum(float v) {
#pragma unroll
  for (int off = 32; off > 0; off >>= 1) v += __shfl_xor(v, off, 64);
  return v;
}

// ---- positional encoding table (T x D) ----
__global__ void pos_kernel(float* __restrict__ pos) {
  int idx = blockIdx.x * 256 + threadIdx.x;
  if (idx >= Tsz * Dsz) return;
  int t = idx / Dsz, d = idx % Dsz;
  float e = (float)(2 * (d >> 1)) / (float)Dsz;
  float den = powf(10000.f, e);
  float a = (float)t / den;
  pos[idx] = (d & 1) ? cosf(a) : sinf(a);
}

// ---- BiN temporal stats: per (b,f) mean + 1/std over S (ddof=1) ----
__global__ void tstat_kernel(const float* __restrict__ x,
                             float* __restrict__ mt, float* __restrict__ rst) {
  int bf = blockIdx.x;
  int b = bf / Fsz, f = bf % Fsz;
  int lane = threadIdx.x;
  const float* xp = x + (size_t)b * Ssz * Fsz + f;
  float s = 0.f, sq = 0.f;
  for (int i = lane; i < Ssz; i += 64) {
    float v = xp[(size_t)i * Fsz];
    s += v; sq += v * v;
  }
  s = wave_sum(s); sq = wave_sum(sq);
  if (lane == 0) {
    float m = s / (float)Ssz;
    float var = (sq - (float)Ssz * m * m) / (float)(Ssz - 1);
    float st = sqrtf(fmaxf(var, 0.f));
    if (st < 1e-4f) st = 1.f;
    mt[bf] = m;
    rst[bf] = 1.f / st;
  }
}

// ---- BiN feature-norm + combine + embedding GEMM + cls + pos (fp32 out h) ----
__global__ __launch_bounds__(64) void embed_kernel(
    const float* __restrict__ x, const float* __restrict__ l1,
    const float* __restrict__ b1, const float* __restrict__ l2,
    const float* __restrict__ b2, const float* __restrict__ y1p,
    const float* __restrict__ y2p, const float* __restrict__ emb_w,
    const float* __restrict__ emb_b, const float* __restrict__ cls,
    const float* __restrict__ pos, const float* __restrict__ mt,
    const float* __restrict__ rst, float* __restrict__ h) {
  int bx = blockIdx.x;
  int b = bx / Tsz, t = bx % Tsz;
  int lane = threadIdx.x;
  float* hp = h + (size_t)bx * Dsz;
  const float* pp = pos + (size_t)t * Dsz;
  if (t == Ssz) {
#pragma unroll
    for (int j = 0; j < 8; ++j) { int d = lane + j * 64; hp[d] = cls[d] + pp[d]; }
    return;
  }
  __shared__ float svec[64];
  float xv = 0.f;
  const float* xp = x + ((size_t)b * Ssz + t) * Fsz;
  if (lane < Fsz) xv = xp[lane];
  float s  = wave_sum(lane < Fsz ? xv : 0.f);
  float sq = wave_sum(lane < Fsz ? xv * xv : 0.f);
  float m = s / (float)Fsz;
  float var = (sq - (float)Fsz * m * m) / (float)(Fsz - 1);
  float sf = sqrtf(fmaxf(var, 0.f));
  if (sf < 1e-4f) sf = 1.f;
  float vec = 0.f;
  if (lane < Fsz) {
    float y1 = y1p[0], y2 = y2p[0];
    float z1 = (xv - m) / sf;
    float X1 = l1[t] * z1 + b1[t];
    int bf = b * Fsz + lane;
    float z2 = (xv - mt[bf]) * rst[bf];
    float X2 = l2[lane] * z2 + b2[lane];
    vec = y1 * X1 + y2 * X2;
  }
  svec[lane] = vec;
  __syncthreads();
#pragma unroll
  for (int j = 0; j < 8; ++j) {
    int d = lane + j * 64;
    float acc = emb_b[d] + pp[d];
    for (int f = 0; f < Fsz; ++f) acc += svec[f] * emb_w[f * Dsz + d];
    hp[d] = acc;
  }
}

// ---- LayerNorm over D=512 (fp32 in, bf16 out) ----
__global__ __launch_bounds__(64) void ln_kernel(
    const float* __restrict__ in, const float* __restrict__ w,
    const float* __restrict__ b, short* __restrict__ out) {
  int row = blockIdx.x, lane = threadIdx.x;
  const float* p = in + (size_t)row * Dsz;
  float4 v0 = *(const float4*)(p + lane * 8);
  float4 v1 = *(const float4*)(p + lane * 8 + 4);
  float s  = v0.x + v0.y + v0.z + v0.w + v1.x + v1.y + v1.z + v1.w;
  float sq = v0.x*v0.x + v0.y*v0.y + v0.z*v0.z + v0.w*v0.w
           + v1.x*v1.x + v1.y*v1.y + v1.z*v1.z + v1.w*v1.w;
  s = wave_sum(s); sq = wave_sum(sq);
  float m = s * (1.f / Dsz);
  float var = sq * (1.f / Dsz) - m * m;
  float r = rsqrtf(var + 1e-5f);
  float4 w0 = *(const float4*)(w + lane * 8);
  float4 w1 = *(const float4*)(w + lane * 8 + 4);
  float4 b0 = *(const float4*)(b + lane * 8);
  float4 b1v = *(const float4*)(b + lane * 8 + 4);
  bf16x8 pk;
  pk[0] = f2bf((v0.x - m) * r * w0.x + b0.x);
  pk[1] = f2bf((v0.y - m) * r * w0.y + b0.y);
  pk[2] = f2bf((v0.z - m) * r * w0.z + b0.z);
  pk[3] = f2bf((v0.w - m) * r * w0.w + b0.w);
  pk[4] = f2bf((v1.x - m) * r * w1.x + b1v.x);
  pk[5] = f2bf((v1.y - m) * r * w1.y + b1v.y);
  pk[6] = f2bf((v1.z - m) * r * w1.z + b1v.z);
  pk[7] = f2bf((v1.w - m) * r * w1.w + b1v.w);
  *(bf16x8*)(out + (size_t)row * Dsz + lane * 8) = pk;
}

// ---- weight convert + transpose: Wt[n][k] = bf16(W[k][n]) ----
__global__ __launch_bounds__(256) void wt_kernel(const float* __restrict__ W,
    short* __restrict__ Wt, int K, int N) {
  __shared__ float t[32][33];
  int k0 = blockIdx.x * 32, n0 = blockIdx.y * 32;
  int tx = threadIdx.x & 31, ty = threadIdx.x >> 5;
#pragma unroll
  for (int r = 0; r < 32; r += 8)
    t[ty + r][tx] = W[(size_t)(k0 + ty + r) * N + n0 + tx];
  __syncthreads();
#pragma unroll
  for (int r = 0; r < 32; r += 8)
    Wt[(size_t)(n0 + ty + r) * K + k0 + tx] = f2bf(t[tx][ty + r]);
}

// ---- bf16 MFMA GEMM: C[Mpad,N] = act(A[Mpad,K]@Bt[N,K]^T + bias) + resid ----
template<int ACT, int OBF>
__global__ __launch_bounds__(256) void mgemm_kernel(
    const short* __restrict__ A, const short* __restrict__ Bt,
    void* __restrict__ Cv, const float* __restrict__ bias,
    const float* __restrict__ resid, int N, int K) {
  __shared__ short As[128 * 32];
  __shared__ short Bs[128 * 32];
  int tid = threadIdx.x;
  int lane = tid & 63, wid = tid >> 6;
  int wr = wid >> 1, wc = wid & 1;
  int m0 = blockIdx.x * 128, n0 = blockIdx.y * 128;
  f32x4 acc[4][4];
#pragma unroll
  for (int i = 0; i < 4; ++i)
#pragma unroll
    for (int j = 0; j < 4; ++j) acc[i][j] = (f32x4){0.f, 0.f, 0.f, 0.f};

  int kq = lane >> 4;
  int rsel = lane & 15;

  for (int kt = 0; kt < K; kt += 32) {
#pragma unroll
    for (int i = 0; i < 2; ++i) {
      int li = i * 256 + tid;
      int row = li >> 2;
      int c8 = (li & 3) ^ (row & 3);
      const short* ga = A + (size_t)(m0 + row) * K + kt + c8 * 8;
      const short* gb = Bt + (size_t)(n0 + row) * K + kt + c8 * 8;
      int base = (i * 256 + wid * 64) * 8;
      __builtin_amdgcn_global_load_lds(
          (const __attribute__((address_space(1))) unsigned int*)ga,
          (__attribute__((address_space(3))) unsigned int*)&As[base], 16, 0, 0);
      __builtin_amdgcn_global_load_lds(
          (const __attribute__((address_space(1))) unsigned int*)gb,
          (__attribute__((address_space(3))) unsigned int*)&Bs[base], 16, 0, 0);
    }
    __syncthreads();
    bf16x8 af[4], bfr[4];
#pragma unroll
    for (int i = 0; i < 4; ++i) {
      int row = wr * 64 + i * 16 + rsel;
      int g = row * 4 + (kq ^ (row & 3));
      af[i] = *(const bf16x8*)&As[g * 8];
      int col = wc * 64 + i * 16 + rsel;
      int gB = col * 4 + (kq ^ (col & 3));
      bfr[i] = *(const bf16x8*)&Bs[gB * 8];
    }
#pragma unroll
    for (int i = 0; i < 4; ++i)
#pragma unroll
      for (int j = 0; j < 4; ++j)
        acc[i][j] = __builtin_amdgcn_mfma_f32_16x16x32_bf16(af[i], bfr[j], acc[i][j], 0, 0, 0);
    __syncthreads();
  }

#pragma unroll
  for (int i = 0; i < 4; ++i) {
    int rbase = m0 + wr * 64 + i * 16 + (lane >> 4) * 4;
#pragma unroll
    for (int j = 0; j < 4; ++j) {
      int gn = n0 + wc * 64 + j * 16 + (lane & 15);
      float bv = bias ? bias[gn] : 0.f;
#pragma unroll
      for (int r = 0; r < 4; ++r) {
        int gm = rbase + r;
        float v = acc[i][j][r] + bv;
        if (ACT == 1) v = 0.5f * v * (1.f + erff(v * 0.70710678118654752f));
        if (resid) v += resid[(size_t)gm * N + gn];
        if (OBF) ((short*)Cv)[(size_t)gm * N + gn] = f2bf(v);
        else     ((float*)Cv)[(size_t)gm * N + gn] = v;
      }
    }
  }
}

// ---- gk low-rank part 1: gk1[m,16] = xn[m,:] @ w1 (bf16 in, fp32 out) ----
__global__ __launch_bounds__(64) void gk1_kernel(const short* __restrict__ xn,
    const float* __restrict__ w1, float* __restrict__ gk1) {
  int m = blockIdx.x, lane = threadIdx.x;
  __shared__ float xr[512];
  bf16x8 v = *(const bf16x8*)(xn + (size_t)m * Dsz + lane * 8);
#pragma unroll
  for (int e = 0; e < 8; ++e) xr[lane * 8 + e] = bf2f(v[e]);
  __syncthreads();
  int c = lane & 15, q = lane >> 4;
  float acc = 0.f;
#pragma unroll 8
  for (int i = 0; i < 128; ++i) {
    int k = q * 128 + i;
    acc += xr[k] * w1[k * 16 + c];
  }
  acc += __shfl_xor(acc, 16, 64);
  acc += __shfl_xor(acc, 32, 64);
  if (lane < 16) gk1[(size_t)m * 16 + c] = acc;
}

// ---- gk low-rank part 2: gke = exp(log_sigmoid(gk1 @ w2 + b2)/16) ----
__global__ __launch_bounds__(256) void gk2_kernel(
    const float* __restrict__ gk1, const float* __restrict__ w2,
    const float* __restrict__ b2, float* __restrict__ gke) {
  int m = blockIdx.x, n = threadIdx.x;
  __shared__ float row[16];
  if (n < 16) row[n] = gk1[(size_t)m * 16 + n];
  __syncthreads();
  float acc = b2[n];
#pragma unroll
  for (int kk = 0; kk < 16; ++kk) acc += row[kk] * w2[kk * 256 + n];
  float z = acc;
  float ls = (z >= 0.f) ? -log1pf(expf(-z)) : z - log1pf(expf(z));
  gke[(size_t)m * 256 + n] = expf(ls * 0.0625f);
}

// ---- scan A: per (b,h,chunk) local scan from S=0 -> A_c (decay prod), B_c ----
__global__ __launch_bounds__(64) void scanA_kernel(
    const float* __restrict__ k, const float* __restrict__ v,
    const float* __restrict__ gke, float* __restrict__ Ac,
    float* __restrict__ Bc) {
  int gid = blockIdx.x;            // bh*NCH + c
  int bh = gid >> 3, c = gid & 7;
  int b = bh >> 3, hh = bh & 7;
  int lane = threadIdx.x;
  int t0 = c * CSZ, t1 = min(t0 + CSZ, Tsz);
  const size_t kbase = (size_t)b * Tsz * DKsz + hh * HKsz;
  const size_t vbase = (size_t)b * Tsz * DVsz + hh * HVsz;
  float S[32];
#pragma unroll
  for (int i = 0; i < 32; ++i) S[i] = 0.f;
  float ac = 1.f;
  for (int t = t0; t < t1; ++t) {
    const float* krow = k + kbase + (size_t)t * DKsz;
    const float* grow = gke + kbase + (size_t)t * DKsz;
    float vv = v[vbase + (size_t)t * DVsz + lane];
    float gl = grow[lane & 31];
    float4 kr[8], gr[8];
#pragma unroll
    for (int j = 0; j < 8; ++j) {
      kr[j] = *(const float4*)(krow + j * 4);
      gr[j] = *(const float4*)(grow + j * 4);
    }
#pragma unroll
    for (int j = 0; j < 8; ++j) {
      S[4*j+0] = S[4*j+0] * gr[j].x + kr[j].x * vv;
      S[4*j+1] = S[4*j+1] * gr[j].y + kr[j].y * vv;
      S[4*j+2] = S[4*j+2] * gr[j].z + kr[j].z * vv;
      S[4*j+3] = S[4*j+3] * gr[j].w + kr[j].w * vv;
    }
    ac *= gl;
  }
  float* bp = Bc + ((size_t)gid * 64 + lane) * 32;
#pragma unroll
  for (int j = 0; j < 8; ++j)
    *(float4*)(bp + j * 4) = make_float4(S[4*j+0], S[4*j+1], S[4*j+2], S[4*j+3]);
  if (lane < 32) Ac[(size_t)gid * 32 + lane] = ac;
}

// ---- scan B: per (b,h) combine chunks; Bc slot c := S_init(c) (in place) ----
__global__ __launch_bounds__(64) void scanB_kernel(
    const float* __restrict__ Ac, float* __restrict__ Bc) {
  int bh = blockIdx.x;
  int lane = threadIdx.x;
  float cur[32];
#pragma unroll
  for (int i = 0; i < 32; ++i) cur[i] = 0.f;
  __shared__ float sA[32];
  for (int c = 0; c < NCH; ++c) {
    size_t gid = (size_t)bh * NCH + c;
    float* bp = Bc + (gid * 64 + lane) * 32;
    __syncthreads();
    if (lane < 32) sA[lane] = Ac[gid * 32 + lane];
    __syncthreads();
    float4 tb[8];
#pragma unroll
    for (int j = 0; j < 8; ++j) tb[j] = *(const float4*)(bp + j * 4);
#pragma unroll
    for (int j = 0; j < 8; ++j)
      *(float4*)(bp + j * 4) = make_float4(cur[4*j+0], cur[4*j+1], cur[4*j+2], cur[4*j+3]);
#pragma unroll
    for (int j = 0; j < 8; ++j) {
      cur[4*j+0] = sA[4*j+0] * cur[4*j+0] + tb[j].x;
      cur[4*j+1] = sA[4*j+1] * cur[4*j+1] + tb[j].y;
      cur[4*j+2] = sA[4*j+2] * cur[4*j+2] + tb[j].z;
      cur[4*j+3] = sA[4*j+3] * cur[4*j+3] + tb[j].w;
    }
  }
}

// ---- scan C: per (b,h,chunk) re-scan from S_init, emit att (bf16) ----
__global__ __launch_bounds__(64) void scanC_kernel(
    const float* __restrict__ q, const float* __restrict__ k,
    const float* __restrict__ v, const float* __restrict__ g,
    const float* __restrict__ gke, const float* __restrict__ gnw,
    const float* __restrict__ Bc, short* __restrict__ att) {
  int gid = blockIdx.x;
  int bh = gid >> 3, c = gid & 7;
  int b = bh >> 3, hh = bh & 7;
  int lane = threadIdx.x;
  int t0 = c * CSZ, t1 = min(t0 + CSZ, Tsz);
  const size_t kbase = (size_t)b * Tsz * DKsz + hh * HKsz;
  const size_t vbase = (size_t)b * Tsz * DVsz + hh * HVsz;
  float S[32];
  const float* sp = Bc + ((size_t)gid * 64 + lane) * 32;
#pragma unroll
  for (int j = 0; j < 8; ++j) {
    float4 sv4 = *(const float4*)(sp + j * 4);
    S[4*j+0] = sv4.x; S[4*j+1] = sv4.y; S[4*j+2] = sv4.z; S[4*j+3] = sv4.w;
  }
  float gn = gnw[lane];
  for (int t = t0; t < t1; ++t) {
    const float* qrow = q + kbase + (size_t)t * DKsz;
    const float* krow = k + kbase + (size_t)t * DKsz;
    const float* grow = gke + kbase + (size_t)t * DKsz;
    float vv = v[vbase + (size_t)t * DVsz + lane];
    float gv = g[vbase + (size_t)t * DVsz + lane];
    float4 kr[8], gr[8], qr[8];
#pragma unroll
    for (int j = 0; j < 8; ++j) {
      qr[j] = *(const float4*)(qrow + j * 4);
      kr[j] = *(const float4*)(krow + j * 4);
      gr[j] = *(const float4*)(grow + j * 4);
    }
    float o = 0.f;
#pragma unroll
    for (int j = 0; j < 8; ++j) {
      S[4*j+0] = S[4*j+0] * gr[j].x + kr[j].x * vv;  o += qr[j].x * S[4*j+0];
      S[4*j+1] = S[4*j+1] * gr[j].y + kr[j].y * vv;  o += qr[j].y * S[4*j+1];
      S[4*j+2] = S[4*j+2] * gr[j].z + kr[j].z * vv;  o += qr[j].z * S[4*j+2];
      S[4*j+3] = S[4*j+3] * gr[j].w + kr[j].w * vv;  o += qr[j].w * S[4*j+3];
    }
    o *= 0.17677669529663689f;   // 32^-0.5
    float ss = wave_sum(o * o);
    float r = rsqrtf(ss * (1.f / 64.f) + 1e-5f);
    float sig = 1.f / (1.f + expf(-gv));
    att[vbase + (size_t)t * DVsz + lane] = f2bf(o * r * gn * gv * sig);
  }
}

// ---- final head ----
__global__ __launch_bounds__(64) void head_kernel(
    const float* __restrict__ h, const float* __restrict__ hw,
    const float* __restrict__ hb, float* __restrict__ out) {
  int b = blockIdx.x, lane = threadIdx.x;
  const float* p = h + ((size_t)b * Tsz + Ssz) * Dsz;
  float p0 = 0.f, p1 = 0.f, p2 = 0.f;
#pragma unroll
  for (int j = 0; j < 8; ++j) {
    int d = lane + j * 64;
    float hv = p[d];
    p0 += hv * hw[d * 3 + 0];
    p1 += hv * hw[d * 3 + 1];
    p2 += hv * hw[d * 3 + 2];
  }
  p0 = wave_sum(p0); p1 = wave_sum(p1); p2 = wave_sum(p2);
  if (lane == 0) {
    out[b * 3 + 0] = p0 + hb[0];
    out[b * 3 + 1] = p1 + hb[1];
    out[b * 3 + 2] = p2 + hb[2];
  }
}

extern "C" void kernel_launch(void* const* d_in, const int* in_sizes, int n_in,
                              void* d_out, int out_size, void* d_ws, size_t ws_size,
                              hipStream_t stream) {
  const float* x       = (const float*)d_in[0];
  const float* bin_l1  = (const float*)d_in[1];
  const float* bin_b1  = (const float*)d_in[2];
  const float* bin_l2  = (const float*)d_in[3];
  const float* bin_b2  = (const float*)d_in[4];
  const float* bin_y1  = (const float*)d_in[5];
  const float* bin_y2  = (const float*)d_in[6];
  const float* emb_w   = (const float*)d_in[7];
  const float* emb_b   = (const float*)d_in[8];
  const float* cls     = (const float*)d_in[9];
  const float* ln1_w   = (const float*)d_in[10];
  const float* ln1_b   = (const float*)d_in[11];
  const float* q_w     = (const float*)d_in[12];
  const float* k_w     = (const float*)d_in[13];
  const float* v_w     = (const float*)d_in[14];
  const float* g_w     = (const float*)d_in[15];
  const float* gk_w1   = (const float*)d_in[16];
  const float* gk_w2   = (const float*)d_in[17];
  const float* gk_b2   = (const float*)d_in[18];
  const float* gnorm_w = (const float*)d_in[19];
  const float* o_w     = (const float*)d_in[20];
  const float* ln2_w   = (const float*)d_in[21];
  const float* ln2_b   = (const float*)d_in[22];
  const float* mlp_w1  = (const float*)d_in[23];
  const float* mlp_b1  = (const float*)d_in[24];
  const float* mlp_w2  = (const float*)d_in[25];
  const float* mlp_b2  = (const float*)d_in[26];
  const float* head_w  = (const float*)d_in[27];
  const float* head_b  = (const float*)d_in[28];
  float* out = (float*)d_out;

  // ---- workspace layout (~193.5 MB, fits proven 196 MB budget) ----
  char* wptr = (char*)d_ws;
  auto alloc = [&](size_t bytes) { char* p = wptr; wptr += (bytes + 255) & ~(size_t)255; return p; };
  float* pos  = (float*)alloc((size_t)Tsz * Dsz * 4);
  float* h    = (float*)alloc((size_t)Mpad * Dsz * 4);
  short* xn   = (short*)alloc((size_t)Mpad * Dsz * 2);   // LN out; aliased as att
  float* qb   = (float*)alloc((size_t)Mpad * DKsz * 4);
  float* kb   = (float*)alloc((size_t)Mpad * DKsz * 4);
  float* gkeb = (float*)alloc((size_t)Mpad * DKsz * 4);
  float* vb   = (float*)alloc((size_t)Mpad * DVsz * 4);
  float* gb   = (float*)alloc((size_t)Mpad * DVsz * 4);
  float* gk1b = (float*)alloc((size_t)Mpad * 16 * 4);
  float* mt   = (float*)alloc((size_t)Bsz * Fsz * 4);
  float* rst  = (float*)alloc((size_t)Bsz * Fsz * 4);
  float* Ac   = (float*)alloc((size_t)Bsz * Hh * NCH * 32 * 4);
  float* Bc   = (float*)alloc((size_t)Bsz * Hh * NCH * 64 * 32 * 4);
  short* wtr  = (short*)alloc((size_t)3145728 * 2);      // single-layer bf16 weights (rotated)
  short* mid  = (short*)qb;      // MLP mid aliases q..g region (dead by then)
  short* att  = xn;              // scan output aliases xn (dead after gk1)

  short* qwT = wtr;
  short* kwT = qwT + 131072;
  short* vwT = kwT + 131072;
  short* gwT = vwT + 262144;
  short* owT = gwT + 262144;
  short* m1T = owT + 262144;
  short* m2T = m1T + 1048576;

  // ---- pre ----
  hipLaunchKernelGGL(pos_kernel, dim3((Tsz * Dsz + 255) / 256), dim3(256), 0, stream, pos);
  hipLaunchKernelGGL(tstat_kernel, dim3(Bsz * Fsz), dim3(64), 0, stream, x, mt, rst);
  hipLaunchKernelGGL(embed_kernel, dim3(Msz), dim3(64), 0, stream,
                     x, bin_l1, bin_b1, bin_l2, bin_b2, bin_y1, bin_y2,
                     emb_w, emb_b, cls, pos, mt, rst, h);

  dim3 blk256(256);
  for (int l = 0; l < Lnum; ++l) {
    // per-layer weight convert (stream-ordered; wtr reused each layer)
    hipLaunchKernelGGL(wt_kernel, dim3(16, 8),  blk256, 0, stream, q_w   + (size_t)l*Dsz*DKsz,   qwT, Dsz, DKsz);
    hipLaunchKernelGGL(wt_kernel, dim3(16, 8),  blk256, 0, stream, k_w   + (size_t)l*Dsz*DKsz,   kwT, Dsz, DKsz);
    hipLaunchKernelGGL(wt_kernel, dim3(16, 16), blk256, 0, stream, v_w   + (size_t)l*Dsz*DVsz,   vwT, Dsz, DVsz);
    hipLaunchKernelGGL(wt_kernel, dim3(16, 16), blk256, 0, stream, g_w   + (size_t)l*Dsz*DVsz,   gwT, Dsz, DVsz);
    hipLaunchKernelGGL(wt_kernel, dim3(16, 16), blk256, 0, stream, o_w   + (size_t)l*DVsz*Dsz,   owT, DVsz, Dsz);
    hipLaunchKernelGGL(wt_kernel, dim3(16, 64), blk256, 0, stream, mlp_w1+ (size_t)l*Dsz*MLPsz,  m1T, Dsz, MLPsz);
    hipLaunchKernelGGL(wt_kernel, dim3(64, 16), blk256, 0, stream, mlp_w2+ (size_t)l*MLPsz*Dsz,  m2T, MLPsz, Dsz);

    const float* lw1 = ln1_w + l * Dsz;  const float* lb1 = ln1_b + l * Dsz;
    const float* g1w = gk_w1 + (size_t)l * Dsz * 16;
    const float* g2w = gk_w2 + (size_t)l * 16 * DKsz;
    const float* g2b = gk_b2 + (size_t)l * DKsz;
    const float* gnw = gnorm_w + l * HVsz;
    const float* lw2 = ln2_w + l * Dsz;  const float* lb2 = ln2_b + l * Dsz;
    const float* m1b = mlp_b1 + (size_t)l * MLPsz;
    const float* m2b = mlp_b2 + (size_t)l * Dsz;

    hipLaunchKernelGGL(ln_kernel, dim3(Msz), dim3(64), 0, stream, h, lw1, lb1, xn);

    hipLaunchKernelGGL((mgemm_kernel<0,0>), dim3(129, 2), blk256, 0, stream,
                       xn, qwT, (void*)qb, (const float*)nullptr, (const float*)nullptr, DKsz, Dsz);
    hipLaunchKernelGGL((mgemm_kernel<0,0>), dim3(129, 2), blk256, 0, stream,
                       xn, kwT, (void*)kb, (const float*)nullptr, (const float*)nullptr, DKsz, Dsz);
    hipLaunchKernelGGL((mgemm_kernel<0,0>), dim3(129, 4), blk256, 0, stream,
                       xn, vwT, (void*)vb, (const float*)nullptr, (const float*)nullptr, DVsz, Dsz);
    hipLaunchKernelGGL((mgemm_kernel<0,0>), dim3(129, 4), blk256, 0, stream,
                       xn, gwT, (void*)gb, (const float*)nullptr, (const float*)nullptr, DVsz, Dsz);
    hipLaunchKernelGGL(gk1_kernel, dim3(Msz), dim3(64), 0, stream, xn, g1w, gk1b);
    hipLaunchKernelGGL(gk2_kernel, dim3(Msz), blk256, 0, stream, gk1b, g2w, g2b, gkeb);

    // chunk-parallel GLA scan
    hipLaunchKernelGGL(scanA_kernel, dim3(Bsz * Hh * NCH), dim3(64), 0, stream,
                       kb, vb, gkeb, Ac, Bc);
    hipLaunchKernelGGL(scanB_kernel, dim3(Bsz * Hh), dim3(64), 0, stream, Ac, Bc);
    hipLaunchKernelGGL(scanC_kernel, dim3(Bsz * Hh * NCH), dim3(64), 0, stream,
                       qb, kb, vb, gb, gkeb, gnw, Bc, att);

    // h = h + att @ o_w
    hipLaunchKernelGGL((mgemm_kernel<0,0>), dim3(129, 4), blk256, 0, stream,
                       att, owT, (void*)h, (const float*)nullptr, h, Dsz, DVsz);

    hipLaunchKernelGGL(ln_kernel, dim3(Msz), dim3(64), 0, stream, h, lw2, lb2, xn);
    // mid = gelu(xn @ w1 + b1)   (bf16 out)
    hipLaunchKernelGGL((mgemm_kernel<1,1>), dim3(129, 16), blk256, 0, stream,
                       xn, m1T, (void*)mid, m1b, (const float*)nullptr, MLPsz, Dsz);
    // h = h + mid @ w2 + b2
    hipLaunchKernelGGL((mgemm_kernel<0,0>), dim3(129, 4), blk256, 0, stream,
                       mid, m2T, (void*)h, m2b, h, Dsz, MLPsz);
  }

  hipLaunchKernelGGL(head_kernel, dim3(Bsz), dim3(64), 0, stream, h, head_w, head_b, out);
}

// Round 4
// 2007.076 us; speedup vs baseline: 3.9853x; 1.0996x over previous
//
#include <hip/hip_runtime.h>
#include <hip/hip_bf16.h>
#include <math.h>

// ---- problem constants ----
#define Bsz   32
#define Ssz   512
#define Fsz   40
#define Dsz   512
#define Hh    8
#define Lnum  4
#define Tsz   513           // S + 1 (cls token)
#define DKsz  256
#define DVsz  512
#define HKsz  32
#define HVsz  64
#define Msz   (Bsz*Tsz)     // 16416 rows
#define Mpad  16512         // 129*128, padded row count for 128-tiles
#define MLPsz 2048
#define NCH   8             // scan chunks per (b,h)
#define CSZ   65            // chunk size (last chunk = 58)
#define QKVG  1536          // packed q|k|v|g row width

typedef __attribute__((ext_vector_type(4))) float f32x4;
typedef __attribute__((ext_vector_type(8))) short bf16x8;

__device__ __forceinline__ float bf2f(short s) {
  unsigned int u = ((unsigned int)(unsigned short)s) << 16;
  return __builtin_bit_cast(float, u);
}
__device__ __forceinline__ short f2bf(float f) {
  __hip_bfloat16 b = __float2bfloat16(f);
  return __builtin_bit_cast(short, b);
}

__device__ __forceinline__ float wave_sum(float v) {
#pragma unroll
  for (int off = 32; off > 0; off >>= 1) v += __shfl_xor(v, off, 64);
  return v;
}

// ---- positional encoding table (T x D) ----
__global__ void pos_kernel(float* __restrict__ pos) {
  int idx = blockIdx.x * 256 + threadIdx.x;
  if (idx >= Tsz * Dsz) return;
  int t = idx / Dsz, d = idx % Dsz;
  float e = (float)(2 * (d >> 1)) / (float)Dsz;
  float den = powf(10000.f, e);
  float a = (float)t / den;
  pos[idx] = (d & 1) ? cosf(a) : sinf(a);
}

// ---- BiN temporal stats: per (b,f) mean + 1/std over S (ddof=1) ----
__global__ void tstat_kernel(const float* __restrict__ x,
                             float* __restrict__ mt, float* __restrict__ rst) {
  int bf = blockIdx.x;
  int b = bf / Fsz, f = bf % Fsz;
  int lane = threadIdx.x;
  const float* xp = x + (size_t)b * Ssz * Fsz + f;
  float s = 0.f, sq = 0.f;
  for (int i = lane; i < Ssz; i += 64) {
    float v = xp[(size_t)i * Fsz];
    s += v; sq += v * v;
  }
  s = wave_sum(s); sq = wave_sum(sq);
  if (lane == 0) {
    float m = s / (float)Ssz;
    float var = (sq - (float)Ssz * m * m) / (float)(Ssz - 1);
    float st = sqrtf(fmaxf(var, 0.f));
    if (st < 1e-4f) st = 1.f;
    mt[bf] = m;
    rst[bf] = 1.f / st;
  }
}

// ---- BiN both norms -> xbT[f][row] (transposed, fp32); zero cls/pad rows ----
__global__ __launch_bounds__(64) void binorm_kernel(
    const float* __restrict__ x, const float* __restrict__ l1,
    const float* __restrict__ b1, const float* __restrict__ l2,
    const float* __restrict__ b2, const float* __restrict__ y1p,
    const float* __restrict__ y2p, const float* __restrict__ mt,
    const float* __restrict__ rst, float* __restrict__ xbT) {
  int row = blockIdx.x;              // 0..Mpad-1
  int lane = threadIdx.x;
  int b = row / Tsz, t = row % Tsz;
  bool valid = (row < Msz) && (t < Ssz);
  if (!valid) {
    if (lane < Fsz) xbT[(size_t)lane * Mpad + row] = 0.f;
    return;
  }
  float xv = 0.f;
  const float* xp = x + ((size_t)b * Ssz + t) * Fsz;
  if (lane < Fsz) xv = xp[lane];
  float s  = wave_sum(lane < Fsz ? xv : 0.f);
  float sq = wave_sum(lane < Fsz ? xv * xv : 0.f);
  float m = s / (float)Fsz;
  float var = (sq - (float)Fsz * m * m) / (float)(Fsz - 1);
  float sf = sqrtf(fmaxf(var, 0.f));
  if (sf < 1e-4f) sf = 1.f;
  if (lane < Fsz) {
    float y1 = y1p[0], y2 = y2p[0];
    float z1 = (xv - m) / sf;
    float X1 = l1[t] * z1 + b1[t];
    int bf = b * Fsz + lane;
    float z2 = (xv - mt[bf]) * rst[bf];
    float X2 = l2[lane] * z2 + b2[lane];
    xbT[(size_t)lane * Mpad + row] = y1 * X1 + y2 * X2;
  }
}

// ---- embed GEMM: h[row][d] = xbT^T @ emb_w + emb_b + pos (cls rows special) ----
__global__ __launch_bounds__(256) void embgemm_kernel(
    const float* __restrict__ xbT, const float* __restrict__ emb_w,
    const float* __restrict__ emb_b, const float* __restrict__ cls,
    const float* __restrict__ pos, float* __restrict__ h) {
  __shared__ float as[Fsz][64];
  __shared__ float bs[Fsz][64];
  int tid = threadIdx.x, tx = tid & 15, ty = tid >> 4;
  int r0 = blockIdx.x * 64, c0 = blockIdx.y * 64;
  for (int idx = tid; idx < Fsz * 64; idx += 256) {
    int f = idx >> 6, r = idx & 63;
    as[f][r] = xbT[(size_t)f * Mpad + r0 + r];
    bs[f][r] = emb_w[f * Dsz + c0 + r];
  }
  __syncthreads();
  float acc[4][4] = {};
#pragma unroll
  for (int f = 0; f < Fsz; ++f) {
    float4 a = *(const float4*)&as[f][ty * 4];
    float4 bv = *(const float4*)&bs[f][tx * 4];
    float av[4] = {a.x, a.y, a.z, a.w};
    float bw[4] = {bv.x, bv.y, bv.z, bv.w};
#pragma unroll
    for (int i = 0; i < 4; ++i)
#pragma unroll
      for (int j = 0; j < 4; ++j) acc[i][j] += av[i] * bw[j];
  }
#pragma unroll
  for (int i = 0; i < 4; ++i) {
    int gm = r0 + ty * 4 + i;
    int t = gm % Tsz;
    const float* pp = pos + (size_t)t * Dsz;
    bool iscls = (t == Ssz);
#pragma unroll
    for (int j = 0; j < 4; ++j) {
      int gn = c0 + tx * 4 + j;
      float v = iscls ? (cls[gn] + pp[gn]) : (acc[i][j] + emb_b[gn] + pp[gn]);
      h[(size_t)gm * Dsz + gn] = v;
    }
  }
}

// ---- LayerNorm over D=512 (fp32 in, bf16 out) ----
__global__ __launch_bounds__(64) void ln_kernel(
    const float* __restrict__ in, const float* __restrict__ w,
    const float* __restrict__ b, short* __restrict__ out) {
  int row = blockIdx.x, lane = threadIdx.x;
  const float* p = in + (size_t)row * Dsz;
  float4 v0 = *(const float4*)(p + lane * 8);
  float4 v1 = *(const float4*)(p + lane * 8 + 4);
  float s  = v0.x + v0.y + v0.z + v0.w + v1.x + v1.y + v1.z + v1.w;
  float sq = v0.x*v0.x + v0.y*v0.y + v0.z*v0.z + v0.w*v0.w
           + v1.x*v1.x + v1.y*v1.y + v1.z*v1.z + v1.w*v1.w;
  s = wave_sum(s); sq = wave_sum(sq);
  float m = s * (1.f / Dsz);
  float var = sq * (1.f / Dsz) - m * m;
  float r = rsqrtf(var + 1e-5f);
  float4 w0 = *(const float4*)(w + lane * 8);
  float4 w1 = *(const float4*)(w + lane * 8 + 4);
  float4 b0 = *(const float4*)(b + lane * 8);
  float4 b1v = *(const float4*)(b + lane * 8 + 4);
  bf16x8 pk;
  pk[0] = f2bf((v0.x - m) * r * w0.x + b0.x);
  pk[1] = f2bf((v0.y - m) * r * w0.y + b0.y);
  pk[2] = f2bf((v0.z - m) * r * w0.z + b0.z);
  pk[3] = f2bf((v0.w - m) * r * w0.w + b0.w);
  pk[4] = f2bf((v1.x - m) * r * w1.x + b1v.x);
  pk[5] = f2bf((v1.y - m) * r * w1.y + b1v.y);
  pk[6] = f2bf((v1.z - m) * r * w1.z + b1v.z);
  pk[7] = f2bf((v1.w - m) * r * w1.w + b1v.w);
  *(bf16x8*)(out + (size_t)row * Dsz + lane * 8) = pk;
}

// ---- weight convert + transpose: Wt[n][k] = bf16(W[k][n]) ----
__global__ __launch_bounds__(256) void wt_kernel(const float* __restrict__ W,
    short* __restrict__ Wt, int K, int N) {
  __shared__ float t[32][33];
  int k0 = blockIdx.x * 32, n0 = blockIdx.y * 32;
  int tx = threadIdx.x & 31, ty = threadIdx.x >> 5;
#pragma unroll
  for (int r = 0; r < 32; r += 8)
    t[ty + r][tx] = W[(size_t)(k0 + ty + r) * N + n0 + tx];
  __syncthreads();
#pragma unroll
  for (int r = 0; r < 32; r += 8)
    Wt[(size_t)(n0 + ty + r) * K + k0 + tx] = f2bf(t[tx][ty + r]);
}

// ---- fused qkvg weight convert: Wt[1536][512] from 4 sources ----
__global__ __launch_bounds__(256) void wt4_kernel(const float* __restrict__ qw,
    const float* __restrict__ kw, const float* __restrict__ vw,
    const float* __restrict__ gw, short* __restrict__ Wt) {
  __shared__ float t[32][33];
  int k0 = blockIdx.x * 32, n0g = blockIdx.y * 32;
  const float* W; int n0, ld;
  if (n0g < 256)       { W = qw; n0 = n0g;        ld = DKsz; }
  else if (n0g < 512)  { W = kw; n0 = n0g - 256;  ld = DKsz; }
  else if (n0g < 1024) { W = vw; n0 = n0g - 512;  ld = DVsz; }
  else                 { W = gw; n0 = n0g - 1024; ld = DVsz; }
  int tx = threadIdx.x & 31, ty = threadIdx.x >> 5;
#pragma unroll
  for (int r = 0; r < 32; r += 8)
    t[ty + r][tx] = W[(size_t)(k0 + ty + r) * ld + n0 + tx];
  __syncthreads();
#pragma unroll
  for (int r = 0; r < 32; r += 8)
    Wt[(size_t)(n0g + ty + r) * Dsz + k0 + tx] = f2bf(t[tx][ty + r]);
}

// ---- bf16 MFMA GEMM: C[Mpad,N] = act(A[Mpad,K]@Bt[N,K]^T + bias) + resid ----
template<int ACT, int OBF>
__global__ __launch_bounds__(256) void mgemm_kernel(
    const short* __restrict__ A, const short* __restrict__ Bt,
    void* __restrict__ Cv, const float* __restrict__ bias,
    const float* __restrict__ resid, int N, int K) {
  __shared__ short As[128 * 32];
  __shared__ short Bs[128 * 32];
  int tid = threadIdx.x;
  int lane = tid & 63, wid = tid >> 6;
  int wr = wid >> 1, wc = wid & 1;
  int m0 = blockIdx.x * 128, n0 = blockIdx.y * 128;
  f32x4 acc[4][4];
#pragma unroll
  for (int i = 0; i < 4; ++i)
#pragma unroll
    for (int j = 0; j < 4; ++j) acc[i][j] = (f32x4){0.f, 0.f, 0.f, 0.f};

  int kq = lane >> 4;
  int rsel = lane & 15;

  for (int kt = 0; kt < K; kt += 32) {
#pragma unroll
    for (int i = 0; i < 2; ++i) {
      int li = i * 256 + tid;
      int row = li >> 2;
      int c8 = (li & 3) ^ (row & 3);
      const short* ga = A + (size_t)(m0 + row) * K + kt + c8 * 8;
      const short* gb = Bt + (size_t)(n0 + row) * K + kt + c8 * 8;
      int base = (i * 256 + wid * 64) * 8;
      __builtin_amdgcn_global_load_lds(
          (const __attribute__((address_space(1))) unsigned int*)ga,
          (__attribute__((address_space(3))) unsigned int*)&As[base], 16, 0, 0);
      __builtin_amdgcn_global_load_lds(
          (const __attribute__((address_space(1))) unsigned int*)gb,
          (__attribute__((address_space(3))) unsigned int*)&Bs[base], 16, 0, 0);
    }
    __syncthreads();
    bf16x8 af[4], bfr[4];
#pragma unroll
    for (int i = 0; i < 4; ++i) {
      int row = wr * 64 + i * 16 + rsel;
      int g = row * 4 + (kq ^ (row & 3));
      af[i] = *(const bf16x8*)&As[g * 8];
      int col = wc * 64 + i * 16 + rsel;
      int gB = col * 4 + (kq ^ (col & 3));
      bfr[i] = *(const bf16x8*)&Bs[gB * 8];
    }
#pragma unroll
    for (int i = 0; i < 4; ++i)
#pragma unroll
      for (int j = 0; j < 4; ++j)
        acc[i][j] = __builtin_amdgcn_mfma_f32_16x16x32_bf16(af[i], bfr[j], acc[i][j], 0, 0, 0);
    __syncthreads();
  }

#pragma unroll
  for (int i = 0; i < 4; ++i) {
    int rbase = m0 + wr * 64 + i * 16 + (lane >> 4) * 4;
#pragma unroll
    for (int j = 0; j < 4; ++j) {
      int gn = n0 + wc * 64 + j * 16 + (lane & 15);
      float bv = bias ? bias[gn] : 0.f;
#pragma unroll
      for (int r = 0; r < 4; ++r) {
        int gm = rbase + r;
        float v = acc[i][j][r] + bv;
        if (ACT == 1) v = 0.5f * v * (1.f + erff(v * 0.70710678118654752f));
        if (resid) v += resid[(size_t)gm * N + gn];
        if (OBF) ((short*)Cv)[(size_t)gm * N + gn] = f2bf(v);
        else     ((float*)Cv)[(size_t)gm * N + gn] = v;
      }
    }
  }
}

// ---- gk low-rank part 1: gk1[m,16] = xn[m,:] @ w1 (bf16 in, fp32 out) ----
__global__ __launch_bounds__(64) void gk1_kernel(const short* __restrict__ xn,
    const float* __restrict__ w1, float* __restrict__ gk1) {
  int m = blockIdx.x, lane = threadIdx.x;
  __shared__ float xr[512];
  bf16x8 v = *(const bf16x8*)(xn + (size_t)m * Dsz + lane * 8);
#pragma unroll
  for (int e = 0; e < 8; ++e) xr[lane * 8 + e] = bf2f(v[e]);
  __syncthreads();
  int c = lane & 15, q = lane >> 4;
  float acc = 0.f;
#pragma unroll 8
  for (int i = 0; i < 128; ++i) {
    int k = q * 128 + i;
    acc += xr[k] * w1[k * 16 + c];
  }
  acc += __shfl_xor(acc, 16, 64);
  acc += __shfl_xor(acc, 32, 64);
  if (lane < 16) gk1[(size_t)m * 16 + c] = acc;
}

// ---- gk low-rank part 2: gke = exp(log_sigmoid(gk1 @ w2 + b2)/16) ----
__global__ __launch_bounds__(256) void gk2_kernel(
    const float* __restrict__ gk1, const float* __restrict__ w2,
    const float* __restrict__ b2, float* __restrict__ gke) {
  int m = blockIdx.x, n = threadIdx.x;
  __shared__ float row[16];
  if (n < 16) row[n] = gk1[(size_t)m * 16 + n];
  __syncthreads();
  float acc = b2[n];
#pragma unroll
  for (int kk = 0; kk < 16; ++kk) acc += row[kk] * w2[kk * 256 + n];
  float z = acc;
  float ls = (z >= 0.f) ? -log1pf(expf(-z)) : z - log1pf(expf(z));
  gke[(size_t)m * 256 + n] = expf(ls * 0.0625f);
}

// ---- scan A: per (b,h,chunk) local scan from S=0 -> A_c (decay prod), B_c ----
__global__ __launch_bounds__(64) void scanA_kernel(
    const float* __restrict__ qkvg, const float* __restrict__ gke,
    float* __restrict__ Ac, float* __restrict__ Bc) {
  int gid = blockIdx.x;            // bh*NCH + c
  int bh = gid >> 3, c = gid & 7;
  int b = bh >> 3, hh = bh & 7;
  int lane = threadIdx.x;
  int t0 = c * CSZ, t1 = min(t0 + CSZ, Tsz);
  const size_t rb = (size_t)b * Tsz;
  float S[32];
#pragma unroll
  for (int i = 0; i < 32; ++i) S[i] = 0.f;
  float ac = 1.f;
  for (int t = t0; t < t1; ++t) {
    const float* base = qkvg + (rb + t) * QKVG;
    const float* krow = base + 256 + hh * HKsz;
    const float* grow = gke + (rb + t) * DKsz + hh * HKsz;
    float vv = base[512 + hh * HVsz + lane];
    float gl = grow[lane & 31];
    float4 kr[8], gr[8];
#pragma unroll
    for (int j = 0; j < 8; ++j) {
      kr[j] = *(const float4*)(krow + j * 4);
      gr[j] = *(const float4*)(grow + j * 4);
    }
#pragma unroll
    for (int j = 0; j < 8; ++j) {
      S[4*j+0] = S[4*j+0] * gr[j].x + kr[j].x * vv;
      S[4*j+1] = S[4*j+1] * gr[j].y + kr[j].y * vv;
      S[4*j+2] = S[4*j+2] * gr[j].z + kr[j].z * vv;
      S[4*j+3] = S[4*j+3] * gr[j].w + kr[j].w * vv;
    }
    ac *= gl;
  }
  float* bp = Bc + ((size_t)gid * 64 + lane) * 32;
#pragma unroll
  for (int j = 0; j < 8; ++j)
    *(float4*)(bp + j * 4) = make_float4(S[4*j+0], S[4*j+1], S[4*j+2], S[4*j+3]);
  if (lane < 32) Ac[(size_t)gid * 32 + lane] = ac;
}

// ---- scan B: per (b,h) combine chunks; Bc slot c := S_init(c) (in place) ----
__global__ __launch_bounds__(64) void scanB_kernel(
    const float* __restrict__ Ac, float* __restrict__ Bc) {
  int bh = blockIdx.x;
  int lane = threadIdx.x;
  float cur[32];
#pragma unroll
  for (int i = 0; i < 32; ++i) cur[i] = 0.f;
  __shared__ float sA[32];
  for (int c = 0; c < NCH; ++c) {
    size_t gid = (size_t)bh * NCH + c;
    float* bp = Bc + (gid * 64 + lane) * 32;
    __syncthreads();
    if (lane < 32) sA[lane] = Ac[gid * 32 + lane];
    __syncthreads();
    float4 tb[8];
#pragma unroll
    for (int j = 0; j < 8; ++j) tb[j] = *(const float4*)(bp + j * 4);
#pragma unroll
    for (int j = 0; j < 8; ++j)
      *(float4*)(bp + j * 4) = make_float4(cur[4*j+0], cur[4*j+1], cur[4*j+2], cur[4*j+3]);
#pragma unroll
    for (int j = 0; j < 8; ++j) {
      cur[4*j+0] = sA[4*j+0] * cur[4*j+0] + tb[j].x;
      cur[4*j+1] = sA[4*j+1] * cur[4*j+1] + tb[j].y;
      cur[4*j+2] = sA[4*j+2] * cur[4*j+2] + tb[j].z;
      cur[4*j+3] = sA[4*j+3] * cur[4*j+3] + tb[j].w;
    }
  }
}

// ---- scan C: per (b,h,chunk) re-scan from S_init, emit att (bf16) ----
__global__ __launch_bounds__(64) void scanC_kernel(
    const float* __restrict__ qkvg, const float* __restrict__ gke,
    const float* __restrict__ gnw, const float* __restrict__ Bc,
    short* __restrict__ att) {
  int gid = blockIdx.x;
  int bh = gid >> 3, c = gid & 7;
  int b = bh >> 3, hh = bh & 7;
  int lane = threadIdx.x;
  int t0 = c * CSZ, t1 = min(t0 + CSZ, Tsz);
  const size_t rb = (size_t)b * Tsz;
  float S[32];
  const float* sp = Bc + ((size_t)gid * 64 + lane) * 32;
#pragma unroll
  for (int j = 0; j < 8; ++j) {
    float4 sv4 = *(const float4*)(sp + j * 4);
    S[4*j+0] = sv4.x; S[4*j+1] = sv4.y; S[4*j+2] = sv4.z; S[4*j+3] = sv4.w;
  }
  float gn = gnw[lane];
  for (int t = t0; t < t1; ++t) {
    const float* base = qkvg + (rb + t) * QKVG;
    const float* qrow = base + hh * HKsz;
    const float* krow = base + 256 + hh * HKsz;
    const float* grow = gke + (rb + t) * DKsz + hh * HKsz;
    float vv = base[512 + hh * HVsz + lane];
    float gv = base[1024 + hh * HVsz + lane];
    float4 kr[8], gr[8], qr[8];
#pragma unroll
    for (int j = 0; j < 8; ++j) {
      qr[j] = *(const float4*)(qrow + j * 4);
      kr[j] = *(const float4*)(krow + j * 4);
      gr[j] = *(const float4*)(grow + j * 4);
    }
    float o = 0.f;
#pragma unroll
    for (int j = 0; j < 8; ++j) {
      S[4*j+0] = S[4*j+0] * gr[j].x + kr[j].x * vv;  o += qr[j].x * S[4*j+0];
      S[4*j+1] = S[4*j+1] * gr[j].y + kr[j].y * vv;  o += qr[j].y * S[4*j+1];
      S[4*j+2] = S[4*j+2] * gr[j].z + kr[j].z * vv;  o += qr[j].z * S[4*j+2];
      S[4*j+3] = S[4*j+3] * gr[j].w + kr[j].w * vv;  o += qr[j].w * S[4*j+3];
    }
    o *= 0.17677669529663689f;   // 32^-0.5
    float ss = wave_sum(o * o);
    float r = rsqrtf(ss * (1.f / 64.f) + 1e-5f);
    float sig = 1.f / (1.f + expf(-gv));
    att[((rb + t) * DVsz) + hh * HVsz + lane] = f2bf(o * r * gn * gv * sig);
  }
}

// ---- final head ----
__global__ __launch_bounds__(64) void head_kernel(
    const float* __restrict__ h, const float* __restrict__ hw,
    const float* __restrict__ hb, float* __restrict__ out) {
  int b = blockIdx.x, lane = threadIdx.x;
  const float* p = h + ((size_t)b * Tsz + Ssz) * Dsz;
  float p0 = 0.f, p1 = 0.f, p2 = 0.f;
#pragma unroll
  for (int j = 0; j < 8; ++j) {
    int d = lane + j * 64;
    float hv = p[d];
    p0 += hv * hw[d * 3 + 0];
    p1 += hv * hw[d * 3 + 1];
    p2 += hv * hw[d * 3 + 2];
  }
  p0 = wave_sum(p0); p1 = wave_sum(p1); p2 = wave_sum(p2);
  if (lane == 0) {
    out[b * 3 + 0] = p0 + hb[0];
    out[b * 3 + 1] = p1 + hb[1];
    out[b * 3 + 2] = p2 + hb[2];
  }
}

extern "C" void kernel_launch(void* const* d_in, const int* in_sizes, int n_in,
                              void* d_out, int out_size, void* d_ws, size_t ws_size,
                              hipStream_t stream) {
  const float* x       = (const float*)d_in[0];
  const float* bin_l1  = (const float*)d_in[1];
  const float* bin_b1  = (const float*)d_in[2];
  const float* bin_l2  = (const float*)d_in[3];
  const float* bin_b2  = (const float*)d_in[4];
  const float* bin_y1  = (const float*)d_in[5];
  const float* bin_y2  = (const float*)d_in[6];
  const float* emb_w   = (const float*)d_in[7];
  const float* emb_b   = (const float*)d_in[8];
  const float* cls     = (const float*)d_in[9];
  const float* ln1_w   = (const float*)d_in[10];
  const float* ln1_b   = (const float*)d_in[11];
  const float* q_w     = (const float*)d_in[12];
  const float* k_w     = (const float*)d_in[13];
  const float* v_w     = (const float*)d_in[14];
  const float* g_w     = (const float*)d_in[15];
  const float* gk_w1   = (const float*)d_in[16];
  const float* gk_w2   = (const float*)d_in[17];
  const float* gk_b2   = (const float*)d_in[18];
  const float* gnorm_w = (const float*)d_in[19];
  const float* o_w     = (const float*)d_in[20];
  const float* ln2_w   = (const float*)d_in[21];
  const float* ln2_b   = (const float*)d_in[22];
  const float* mlp_w1  = (const float*)d_in[23];
  const float* mlp_b1  = (const float*)d_in[24];
  const float* mlp_w2  = (const float*)d_in[25];
  const float* mlp_b2  = (const float*)d_in[26];
  const float* head_w  = (const float*)d_in[27];
  const float* head_b  = (const float*)d_in[28];
  float* out = (float*)d_out;

  // ---- workspace layout (~193.5 MB) ----
  char* wptr = (char*)d_ws;
  auto alloc = [&](size_t bytes) { char* p = wptr; wptr += (bytes + 255) & ~(size_t)255; return p; };
  float* pos  = (float*)alloc((size_t)Tsz * Dsz * 4);
  float* h    = (float*)alloc((size_t)Mpad * Dsz * 4);
  short* xn   = (short*)alloc((size_t)Mpad * Dsz * 2);      // LN out; aliased as att
  float* qkvg = (float*)alloc((size_t)Mpad * QKVG * 4);     // packed q|k|v|g (also xbT, mid)
  float* gkeb = (float*)alloc((size_t)Mpad * DKsz * 4);
  float* gk1b = (float*)alloc((size_t)Mpad * 16 * 4);
  float* mt   = (float*)alloc((size_t)Bsz * Fsz * 4);
  float* rst  = (float*)alloc((size_t)Bsz * Fsz * 4);
  float* Ac   = (float*)alloc((size_t)Bsz * Hh * NCH * 32 * 4);
  float* Bc   = (float*)alloc((size_t)Bsz * Hh * NCH * 64 * 32 * 4);
  short* wtr  = (short*)alloc((size_t)3145728 * 2);         // per-layer bf16 weights
  float* xbT  = qkvg;            // [40][Mpad] fp32, dead before qkvg GEMM
  short* mid  = (short*)qkvg;    // MLP mid bf16, aliases qkvg (dead by MLP)
  short* att  = xn;              // scan output aliases xn (dead after gk1)

  short* qkvgT = wtr;                         // [1536][512]
  short* owT   = qkvgT + 786432;
  short* m1T   = owT + 262144;
  short* m2T   = m1T + 1048576;

  // ---- pre ----
  hipLaunchKernelGGL(pos_kernel, dim3((Tsz * Dsz + 255) / 256), dim3(256), 0, stream, pos);
  hipLaunchKernelGGL(tstat_kernel, dim3(Bsz * Fsz), dim3(64), 0, stream, x, mt, rst);
  hipLaunchKernelGGL(binorm_kernel, dim3(Mpad), dim3(64), 0, stream,
                     x, bin_l1, bin_b1, bin_l2, bin_b2, bin_y1, bin_y2, mt, rst, xbT);
  hipLaunchKernelGGL(embgemm_kernel, dim3(258, 8), dim3(256), 0, stream,
                     xbT, emb_w, emb_b, cls, pos, h);

  dim3 blk256(256);
  for (int l = 0; l < Lnum; ++l) {
    // per-layer weight convert (stream-ordered; wtr reused each layer)
    hipLaunchKernelGGL(wt4_kernel, dim3(16, 48), blk256, 0, stream,
                       q_w + (size_t)l*Dsz*DKsz, k_w + (size_t)l*Dsz*DKsz,
                       v_w + (size_t)l*Dsz*DVsz, g_w + (size_t)l*Dsz*DVsz, qkvgT);
    hipLaunchKernelGGL(wt_kernel, dim3(16, 16), blk256, 0, stream, o_w   + (size_t)l*DVsz*Dsz,  owT, DVsz, Dsz);
    hipLaunchKernelGGL(wt_kernel, dim3(16, 64), blk256, 0, stream, mlp_w1+ (size_t)l*Dsz*MLPsz, m1T, Dsz, MLPsz);
    hipLaunchKernelGGL(wt_kernel, dim3(64, 16), blk256, 0, stream, mlp_w2+ (size_t)l*MLPsz*Dsz, m2T, MLPsz, Dsz);

    const float* lw1 = ln1_w + l * Dsz;  const float* lb1 = ln1_b + l * Dsz;
    const float* g1w = gk_w1 + (size_t)l * Dsz * 16;
    const float* g2w = gk_w2 + (size_t)l * 16 * DKsz;
    const float* g2b = gk_b2 + (size_t)l * DKsz;
    const float* gnw = gnorm_w + l * HVsz;
    const float* lw2 = ln2_w + l * Dsz;  const float* lb2 = ln2_b + l * Dsz;
    const float* m1b = mlp_b1 + (size_t)l * MLPsz;
    const float* m2b = mlp_b2 + (size_t)l * Dsz;

    hipLaunchKernelGGL(ln_kernel, dim3(Msz), dim3(64), 0, stream, h, lw1, lb1, xn);

    // packed q|k|v|g projection (N=1536)
    hipLaunchKernelGGL((mgemm_kernel<0,0>), dim3(129, 12), blk256, 0, stream,
                       xn, qkvgT, (void*)qkvg, (const float*)nullptr, (const float*)nullptr, QKVG, Dsz);
    hipLaunchKernelGGL(gk1_kernel, dim3(Msz), dim3(64), 0, stream, xn, g1w, gk1b);
    hipLaunchKernelGGL(gk2_kernel, dim3(Msz), blk256, 0, stream, gk1b, g2w, g2b, gkeb);

    // chunk-parallel GLA scan
    hipLaunchKernelGGL(scanA_kernel, dim3(Bsz * Hh * NCH), dim3(64), 0, stream,
                       qkvg, gkeb, Ac, Bc);
    hipLaunchKernelGGL(scanB_kernel, dim3(Bsz * Hh), dim3(64), 0, stream, Ac, Bc);
    hipLaunchKernelGGL(scanC_kernel, dim3(Bsz * Hh * NCH), dim3(64), 0, stream,
                       qkvg, gkeb, gnw, Bc, att);

    // h = h + att @ o_w
    hipLaunchKernelGGL((mgemm_kernel<0,0>), dim3(129, 4), blk256, 0, stream,
                       att, owT, (void*)h, (const float*)nullptr, h, Dsz, DVsz);

    hipLaunchKernelGGL(ln_kernel, dim3(Msz), dim3(64), 0, stream, h, lw2, lb2, xn);
    // mid = gelu(xn @ w1 + b1)   (bf16 out)
    hipLaunchKernelGGL((mgemm_kernel<1,1>), dim3(129, 16), blk256, 0, stream,
                       xn, m1T, (void*)mid, m1b, (const float*)nullptr, MLPsz, Dsz);
    // h = h + mid @ w2 + b2
    hipLaunchKernelGGL((mgemm_kernel<0,0>), dim3(129, 4), blk256, 0, stream,
                       mid, m2T, (void*)h, m2b, h, Dsz, MLPsz);
  }

  hipLaunchKernelGGL(head_kernel, dim3(Bsz), dim3(64), 0, stream, h, head_w, head_b, out);
}

// Round 5
// 1806.058 us; speedup vs baseline: 4.4289x; 1.1113x over previous
//
#include <hip/hip_runtime.h>
#include <hip/hip_bf16.h>
#include <math.h>

// ---- problem constants ----
#define Bsz   32
#define Ssz   512
#define Fsz   40
#define Dsz   512
#define Hh    8
#define Lnum  4
#define Tsz   513           // S + 1 (cls token)
#define DKsz  256
#define DVsz  512
#define HKsz  32
#define HVsz  64
#define Msz   (Bsz*Tsz)     // 16416 rows
#define Mpad  16512         // 129*128, padded row count for 128-tiles
#define MLPsz 2048
#define NCH   8             // scan chunks per (b,h)
#define CSZ   65            // chunk size (last chunk = 58)
#define QKVG  1536          // packed q|k|v|g row width

typedef __attribute__((ext_vector_type(4))) float f32x4;
typedef __attribute__((ext_vector_type(8))) short bf16x8;

__device__ __forceinline__ float bf2f(short s) {
  unsigned int u = ((unsigned int)(unsigned short)s) << 16;
  return __builtin_bit_cast(float, u);
}
__device__ __forceinline__ short f2bf(float f) {
  __hip_bfloat16 b = __float2bfloat16(f);
  return __builtin_bit_cast(short, b);
}

__device__ __forceinline__ float wave_sum(float v) {
#pragma unroll
  for (int off = 32; off > 0; off >>= 1) v += __shfl_xor(v, off, 64);
  return v;
}

// ---- positional encoding table (T x D) ----
__global__ void pos_kernel(float* __restrict__ pos) {
  int idx = blockIdx.x * 256 + threadIdx.x;
  if (idx >= Tsz * Dsz) return;
  int t = idx / Dsz, d = idx % Dsz;
  float e = (float)(2 * (d >> 1)) / (float)Dsz;
  float den = powf(10000.f, e);
  float a = (float)t / den;
  pos[idx] = (d & 1) ? cosf(a) : sinf(a);
}

// ---- BiN temporal stats: per (b,f) mean + 1/std over S (ddof=1) ----
__global__ void tstat_kernel(const float* __restrict__ x,
                             float* __restrict__ mt, float* __restrict__ rst) {
  int bf = blockIdx.x;
  int b = bf / Fsz, f = bf % Fsz;
  int lane = threadIdx.x;
  const float* xp = x + (size_t)b * Ssz * Fsz + f;
  float s = 0.f, sq = 0.f;
  for (int i = lane; i < Ssz; i += 64) {
    float v = xp[(size_t)i * Fsz];
    s += v; sq += v * v;
  }
  s = wave_sum(s); sq = wave_sum(sq);
  if (lane == 0) {
    float m = s / (float)Ssz;
    float var = (sq - (float)Ssz * m * m) / (float)(Ssz - 1);
    float st = sqrtf(fmaxf(var, 0.f));
    if (st < 1e-4f) st = 1.f;
    mt[bf] = m;
    rst[bf] = 1.f / st;
  }
}

// ---- BiN both norms -> xbT[f][row] (transposed, fp32); zero cls/pad rows ----
__global__ __launch_bounds__(64) void binorm_kernel(
    const float* __restrict__ x, const float* __restrict__ l1,
    const float* __restrict__ b1, const float* __restrict__ l2,
    const float* __restrict__ b2, const float* __restrict__ y1p,
    const float* __restrict__ y2p, const float* __restrict__ mt,
    const float* __restrict__ rst, float* __restrict__ xbT) {
  int row = blockIdx.x;              // 0..Mpad-1
  int lane = threadIdx.x;
  int b = row / Tsz, t = row % Tsz;
  bool valid = (row < Msz) && (t < Ssz);
  if (!valid) {
    if (lane < Fsz) xbT[(size_t)lane * Mpad + row] = 0.f;
    return;
  }
  float xv = 0.f;
  const float* xp = x + ((size_t)b * Ssz + t) * Fsz;
  if (lane < Fsz) xv = xp[lane];
  float s  = wave_sum(lane < Fsz ? xv : 0.f);
  float sq = wave_sum(lane < Fsz ? xv * xv : 0.f);
  float m = s / (float)Fsz;
  float var = (sq - (float)Fsz * m * m) / (float)(Fsz - 1);
  float sf = sqrtf(fmaxf(var, 0.f));
  if (sf < 1e-4f) sf = 1.f;
  if (lane < Fsz) {
    float y1 = y1p[0], y2 = y2p[0];
    float z1 = (xv - m) / sf;
    float X1 = l1[t] * z1 + b1[t];
    int bf = b * Fsz + lane;
    float z2 = (xv - mt[bf]) * rst[bf];
    float X2 = l2[lane] * z2 + b2[lane];
    xbT[(size_t)lane * Mpad + row] = y1 * X1 + y2 * X2;
  }
}

// ---- embed GEMM: h[row][d] = xbT^T @ emb_w + emb_b + pos (cls rows special) ----
// launch_bounds(256,4): cap VGPR at 128 -> 4 blocks/CU (was 176 VGPR / 2 blocks)
__global__ __launch_bounds__(256, 4) void embgemm_kernel(
    const float* __restrict__ xbT, const float* __restrict__ emb_w,
    const float* __restrict__ emb_b, const float* __restrict__ cls,
    const float* __restrict__ pos, float* __restrict__ h) {
  __shared__ float as[Fsz][64];
  __shared__ float bs[Fsz][64];
  int tid = threadIdx.x, tx = tid & 15, ty = tid >> 4;
  int r0 = blockIdx.x * 64, c0 = blockIdx.y * 64;
  for (int idx = tid; idx < Fsz * 64; idx += 256) {
    int f = idx >> 6, r = idx & 63;
    as[f][r] = xbT[(size_t)f * Mpad + r0 + r];
    bs[f][r] = emb_w[f * Dsz + c0 + r];
  }
  __syncthreads();
  float acc[4][4] = {};
#pragma unroll 5
  for (int f = 0; f < Fsz; ++f) {
    float4 a = *(const float4*)&as[f][ty * 4];
    float4 bv = *(const float4*)&bs[f][tx * 4];
    float av[4] = {a.x, a.y, a.z, a.w};
    float bw[4] = {bv.x, bv.y, bv.z, bv.w};
#pragma unroll
    for (int i = 0; i < 4; ++i)
#pragma unroll
      for (int j = 0; j < 4; ++j) acc[i][j] += av[i] * bw[j];
  }
#pragma unroll
  for (int i = 0; i < 4; ++i) {
    int gm = r0 + ty * 4 + i;
    int t = gm % Tsz;
    const float* pp = pos + (size_t)t * Dsz;
    bool iscls = (t == Ssz);
    int gn = c0 + tx * 4;
#pragma unroll
    for (int j = 0; j < 4; ++j) {
      float v = iscls ? (cls[gn + j] + pp[gn + j])
                      : (acc[i][j] + emb_b[gn + j] + pp[gn + j]);
      h[(size_t)gm * Dsz + gn + j] = v;
    }
  }
}

// ---- LayerNorm over D=512 (fp32 in, bf16 out) ----
__global__ __launch_bounds__(64) void ln_kernel(
    const float* __restrict__ in, const float* __restrict__ w,
    const float* __restrict__ b, short* __restrict__ out) {
  int row = blockIdx.x, lane = threadIdx.x;
  const float* p = in + (size_t)row * Dsz;
  float4 v0 = *(const float4*)(p + lane * 8);
  float4 v1 = *(const float4*)(p + lane * 8 + 4);
  float s  = v0.x + v0.y + v0.z + v0.w + v1.x + v1.y + v1.z + v1.w;
  float sq = v0.x*v0.x + v0.y*v0.y + v0.z*v0.z + v0.w*v0.w
           + v1.x*v1.x + v1.y*v1.y + v1.z*v1.z + v1.w*v1.w;
  s = wave_sum(s); sq = wave_sum(sq);
  float m = s * (1.f / Dsz);
  float var = sq * (1.f / Dsz) - m * m;
  float r = rsqrtf(var + 1e-5f);
  float4 w0 = *(const float4*)(w + lane * 8);
  float4 w1 = *(const float4*)(w + lane * 8 + 4);
  float4 b0 = *(const float4*)(b + lane * 8);
  float4 b1v = *(const float4*)(b + lane * 8 + 4);
  bf16x8 pk;
  pk[0] = f2bf((v0.x - m) * r * w0.x + b0.x);
  pk[1] = f2bf((v0.y - m) * r * w0.y + b0.y);
  pk[2] = f2bf((v0.z - m) * r * w0.z + b0.z);
  pk[3] = f2bf((v0.w - m) * r * w0.w + b0.w);
  pk[4] = f2bf((v1.x - m) * r * w1.x + b1v.x);
  pk[5] = f2bf((v1.y - m) * r * w1.y + b1v.y);
  pk[6] = f2bf((v1.z - m) * r * w1.z + b1v.z);
  pk[7] = f2bf((v1.w - m) * r * w1.w + b1v.w);
  *(bf16x8*)(out + (size_t)row * Dsz + lane * 8) = pk;
}

// ---- weight convert + transpose: Wt[n][k] = bf16(W[k][n]) ----
__global__ __launch_bounds__(256) void wt_kernel(const float* __restrict__ W,
    short* __restrict__ Wt, int K, int N) {
  __shared__ float t[32][33];
  int k0 = blockIdx.x * 32, n0 = blockIdx.y * 32;
  int tx = threadIdx.x & 31, ty = threadIdx.x >> 5;
#pragma unroll
  for (int r = 0; r < 32; r += 8)
    t[ty + r][tx] = W[(size_t)(k0 + ty + r) * N + n0 + tx];
  __syncthreads();
#pragma unroll
  for (int r = 0; r < 32; r += 8)
    Wt[(size_t)(n0 + ty + r) * K + k0 + tx] = f2bf(t[tx][ty + r]);
}

// ---- fused qkvg weight convert: Wt[1536][512] from 4 sources ----
__global__ __launch_bounds__(256) void wt4_kernel(const float* __restrict__ qw,
    const float* __restrict__ kw, const float* __restrict__ vw,
    const float* __restrict__ gw, short* __restrict__ Wt) {
  __shared__ float t[32][33];
  int k0 = blockIdx.x * 32, n0g = blockIdx.y * 32;
  const float* W; int n0, ld;
  if (n0g < 256)       { W = qw; n0 = n0g;        ld = DKsz; }
  else if (n0g < 512)  { W = kw; n0 = n0g - 256;  ld = DKsz; }
  else if (n0g < 1024) { W = vw; n0 = n0g - 512;  ld = DVsz; }
  else                 { W = gw; n0 = n0g - 1024; ld = DVsz; }
  int tx = threadIdx.x & 31, ty = threadIdx.x >> 5;
#pragma unroll
  for (int r = 0; r < 32; r += 8)
    t[ty + r][tx] = W[(size_t)(k0 + ty + r) * ld + n0 + tx];
  __syncthreads();
#pragma unroll
  for (int r = 0; r < 32; r += 8)
    Wt[(size_t)(n0g + ty + r) * Dsz + k0 + tx] = f2bf(t[tx][ty + r]);
}

// ---- bf16 MFMA GEMM, BK=64: C = act(A[Mpad,K]@Bt[N,K]^T + bias) + resid ----
// 128x128 tile, 4 waves, 4x4 frags of 16x16x32; 2 MFMA k-steps per barrier.
template<int ACT, int OBF>
__global__ __launch_bounds__(256) void mgemm_kernel(
    const short* __restrict__ A, const short* __restrict__ Bt,
    void* __restrict__ Cv, const float* __restrict__ bias,
    const float* __restrict__ resid, int N, int K) {
  __shared__ short As[128 * 64];
  __shared__ short Bs[128 * 64];
  int tid = threadIdx.x;
  int lane = tid & 63, wid = tid >> 6;
  int wr = wid >> 1, wc = wid & 1;
  int m0 = blockIdx.x * 128, n0 = blockIdx.y * 128;
  f32x4 acc[4][4];
#pragma unroll
  for (int i = 0; i < 4; ++i)
#pragma unroll
    for (int j = 0; j < 4; ++j) acc[i][j] = (f32x4){0.f, 0.f, 0.f, 0.f};

  int kq = lane >> 4;          // k-quarter within 32-col sub-block
  int rsel = lane & 15;

  for (int kt = 0; kt < K; kt += 64) {
    // stage 128x64 A-tile + B-tile; 8 granules/row, XOR-swizzled source (rule #21)
#pragma unroll
    for (int i = 0; i < 4; ++i) {
      int li = i * 256 + tid;                 // granule 0..1023
      int row = li >> 3;
      int gsrc = (li & 7) ^ (row & 7);
      const short* ga = A + (size_t)(m0 + row) * K + kt + gsrc * 8;
      const short* gb = Bt + (size_t)(n0 + row) * K + kt + gsrc * 8;
      int base = (i * 256 + wid * 64) * 8;    // wave-uniform LDS granule base
      __builtin_amdgcn_global_load_lds(
          (const __attribute__((address_space(1))) unsigned int*)ga,
          (__attribute__((address_space(3))) unsigned int*)&As[base], 16, 0, 0);
      __builtin_amdgcn_global_load_lds(
          (const __attribute__((address_space(1))) unsigned int*)gb,
          (__attribute__((address_space(3))) unsigned int*)&Bs[base], 16, 0, 0);
    }
    __syncthreads();
#pragma unroll
    for (int s = 0; s < 2; ++s) {
      bf16x8 af[4], bfr[4];
#pragma unroll
      for (int i = 0; i < 4; ++i) {
        int row = wr * 64 + i * 16 + rsel;
        int slot = (s * 4 + kq) ^ (row & 7);
        af[i] = *(const bf16x8*)&As[row * 64 + slot * 8];
        int col = wc * 64 + i * 16 + rsel;
        int slotB = (s * 4 + kq) ^ (col & 7);
        bfr[i] = *(const bf16x8*)&Bs[col * 64 + slotB * 8];
      }
#pragma unroll
      for (int i = 0; i < 4; ++i)
#pragma unroll
        for (int j = 0; j < 4; ++j)
          acc[i][j] = __builtin_amdgcn_mfma_f32_16x16x32_bf16(af[i], bfr[j], acc[i][j], 0, 0, 0);
    }
    __syncthreads();
  }

#pragma unroll
  for (int i = 0; i < 4; ++i) {
    int rbase = m0 + wr * 64 + i * 16 + (lane >> 4) * 4;
#pragma unroll
    for (int j = 0; j < 4; ++j) {
      int gn = n0 + wc * 64 + j * 16 + (lane & 15);
      float bv = bias ? bias[gn] : 0.f;
#pragma unroll
      for (int r = 0; r < 4; ++r) {
        int gm = rbase + r;
        float v = acc[i][j][r] + bv;
        if (ACT == 1) v = 0.5f * v * (1.f + erff(v * 0.70710678118654752f));
        if (resid) v += resid[(size_t)gm * N + gn];
        if (OBF) ((short*)Cv)[(size_t)gm * N + gn] = f2bf(v);
        else     ((float*)Cv)[(size_t)gm * N + gn] = v;
      }
    }
  }
}

// ---- gk low-rank part 1: gk1[m,16] = xn[m,:] @ w1 (bf16 in, fp32 out) ----
__global__ __launch_bounds__(64) void gk1_kernel(const short* __restrict__ xn,
    const float* __restrict__ w1, float* __restrict__ gk1) {
  int m = blockIdx.x, lane = threadIdx.x;
  __shared__ float xr[512];
  bf16x8 v = *(const bf16x8*)(xn + (size_t)m * Dsz + lane * 8);
#pragma unroll
  for (int e = 0; e < 8; ++e) xr[lane * 8 + e] = bf2f(v[e]);
  __syncthreads();
  int c = lane & 15, q = lane >> 4;
  float acc = 0.f;
#pragma unroll 8
  for (int i = 0; i < 128; ++i) {
    int k = q * 128 + i;
    acc += xr[k] * w1[k * 16 + c];
  }
  acc += __shfl_xor(acc, 16, 64);
  acc += __shfl_xor(acc, 32, 64);
  if (lane < 16) gk1[(size_t)m * 16 + c] = acc;
}

// ---- gk low-rank part 2: gke = exp(log_sigmoid(gk1 @ w2 + b2)/16) ----
__global__ __launch_bounds__(256) void gk2_kernel(
    const float* __restrict__ gk1, const float* __restrict__ w2,
    const float* __restrict__ b2, float* __restrict__ gke) {
  int m = blockIdx.x, n = threadIdx.x;
  __shared__ float row[16];
  if (n < 16) row[n] = gk1[(size_t)m * 16 + n];
  __syncthreads();
  float acc = b2[n];
#pragma unroll
  for (int kk = 0; kk < 16; ++kk) acc += row[kk] * w2[kk * 256 + n];
  float z = acc;
  float ls = (z >= 0.f) ? -log1pf(expf(-z)) : z - log1pf(expf(z));
  gke[(size_t)m * 256 + n] = expf(ls * 0.0625f);
}

// ---- scan A: per (b,h,chunk) local scan from S=0 -> A_c (decay prod), B_c ----
__global__ __launch_bounds__(64) void scanA_kernel(
    const float* __restrict__ qkvg, const float* __restrict__ gke,
    float* __restrict__ Ac, float* __restrict__ Bc) {
  int gid = blockIdx.x;            // bh*NCH + c
  int bh = gid >> 3, c = gid & 7;
  int b = bh >> 3, hh = bh & 7;
  int lane = threadIdx.x;
  int t0 = c * CSZ, t1 = min(t0 + CSZ, Tsz);
  const size_t rb = (size_t)b * Tsz;
  float S[32];
#pragma unroll
  for (int i = 0; i < 32; ++i) S[i] = 0.f;
  float ac = 1.f;
  for (int t = t0; t < t1; ++t) {
    const float* base = qkvg + (rb + t) * QKVG;
    const float* krow = base + 256 + hh * HKsz;
    const float* grow = gke + (rb + t) * DKsz + hh * HKsz;
    float vv = base[512 + hh * HVsz + lane];
    float gl = grow[lane & 31];
    float4 kr[8], gr[8];
#pragma unroll
    for (int j = 0; j < 8; ++j) {
      kr[j] = *(const float4*)(krow + j * 4);
      gr[j] = *(const float4*)(grow + j * 4);
    }
#pragma unroll
    for (int j = 0; j < 8; ++j) {
      S[4*j+0] = S[4*j+0] * gr[j].x + kr[j].x * vv;
      S[4*j+1] = S[4*j+1] * gr[j].y + kr[j].y * vv;
      S[4*j+2] = S[4*j+2] * gr[j].z + kr[j].z * vv;
      S[4*j+3] = S[4*j+3] * gr[j].w + kr[j].w * vv;
    }
    ac *= gl;
  }
  float* bp = Bc + ((size_t)gid * 64 + lane) * 32;
#pragma unroll
  for (int j = 0; j < 8; ++j)
    *(float4*)(bp + j * 4) = make_float4(S[4*j+0], S[4*j+1], S[4*j+2], S[4*j+3]);
  if (lane < 32) Ac[(size_t)gid * 32 + lane] = ac;
}

// ---- scan B: per (b,h) combine chunks; Bc slot c := S_init(c) (in place) ----
__global__ __launch_bounds__(64) void scanB_kernel(
    const float* __restrict__ Ac, float* __restrict__ Bc) {
  int bh = blockIdx.x;
  int lane = threadIdx.x;
  float cur[32];
#pragma unroll
  for (int i = 0; i < 32; ++i) cur[i] = 0.f;
  __shared__ float sA[32];
  for (int c = 0; c < NCH; ++c) {
    size_t gid = (size_t)bh * NCH + c;
    float* bp = Bc + (gid * 64 + lane) * 32;
    __syncthreads();
    if (lane < 32) sA[lane] = Ac[gid * 32 + lane];
    __syncthreads();
    float4 tb[8];
#pragma unroll
    for (int j = 0; j < 8; ++j) tb[j] = *(const float4*)(bp + j * 4);
#pragma unroll
    for (int j = 0; j < 8; ++j)
      *(float4*)(bp + j * 4) = make_float4(cur[4*j+0], cur[4*j+1], cur[4*j+2], cur[4*j+3]);
#pragma unroll
    for (int j = 0; j < 8; ++j) {
      cur[4*j+0] = sA[4*j+0] * cur[4*j+0] + tb[j].x;
      cur[4*j+1] = sA[4*j+1] * cur[4*j+1] + tb[j].y;
      cur[4*j+2] = sA[4*j+2] * cur[4*j+2] + tb[j].z;
      cur[4*j+3] = sA[4*j+3] * cur[4*j+3] + tb[j].w;
    }
  }
}

// ---- scan C: per (b,h,chunk) re-scan from S_init, emit att (bf16) ----
__global__ __launch_bounds__(64) void scanC_kernel(
    const float* __restrict__ qkvg, const float* __restrict__ gke,
    const float* __restrict__ gnw, const float* __restrict__ Bc,
    short* __restrict__ att) {
  int gid = blockIdx.x;
  int bh = gid >> 3, c = gid & 7;
  int b = bh >> 3, hh = bh & 7;
  int lane = threadIdx.x;
  int t0 = c * CSZ, t1 = min(t0 + CSZ, Tsz);
  const size_t rb = (size_t)b * Tsz;
  float S[32];
  const float* sp = Bc + ((size_t)gid * 64 + lane) * 32;
#pragma unroll
  for (int j = 0; j < 8; ++j) {
    float4 sv4 = *(const float4*)(sp + j * 4);
    S[4*j+0] = sv4.x; S[4*j+1] = sv4.y; S[4*j+2] = sv4.z; S[4*j+3] = sv4.w;
  }
  float gn = gnw[lane];
  for (int t = t0; t < t1; ++t) {
    const float* base = qkvg + (rb + t) * QKVG;
    const float* qrow = base + hh * HKsz;
    const float* krow = base + 256 + hh * HKsz;
    const float* grow = gke + (rb + t) * DKsz + hh * HKsz;
    float vv = base[512 + hh * HVsz + lane];
    float gv = base[1024 + hh * HVsz + lane];
    float4 kr[8], gr[8], qr[8];
#pragma unroll
    for (int j = 0; j < 8; ++j) {
      qr[j] = *(const float4*)(qrow + j * 4);
      kr[j] = *(const float4*)(krow + j * 4);
      gr[j] = *(const float4*)(grow + j * 4);
    }
    float o = 0.f;
#pragma unroll
    for (int j = 0; j < 8; ++j) {
      S[4*j+0] = S[4*j+0] * gr[j].x + kr[j].x * vv;  o += qr[j].x * S[4*j+0];
      S[4*j+1] = S[4*j+1] * gr[j].y + kr[j].y * vv;  o += qr[j].y * S[4*j+1];
      S[4*j+2] = S[4*j+2] * gr[j].z + kr[j].z * vv;  o += qr[j].z * S[4*j+2];
      S[4*j+3] = S[4*j+3] * gr[j].w + kr[j].w * vv;  o += qr[j].w * S[4*j+3];
    }
    o *= 0.17677669529663689f;   // 32^-0.5
    float ss = wave_sum(o * o);
    float r = rsqrtf(ss * (1.f / 64.f) + 1e-5f);
    float sig = 1.f / (1.f + expf(-gv));
    att[((rb + t) * DVsz) + hh * HVsz + lane] = f2bf(o * r * gn * gv * sig);
  }
}

// ---- final head ----
__global__ __launch_bounds__(64) void head_kernel(
    const float* __restrict__ h, const float* __restrict__ hw,
    const float* __restrict__ hb, float* __restrict__ out) {
  int b = blockIdx.x, lane = threadIdx.x;
  const float* p = h + ((size_t)b * Tsz + Ssz) * Dsz;
  float p0 = 0.f, p1 = 0.f, p2 = 0.f;
#pragma unroll
  for (int j = 0; j < 8; ++j) {
    int d = lane + j * 64;
    float hv = p[d];
    p0 += hv * hw[d * 3 + 0];
    p1 += hv * hw[d * 3 + 1];
    p2 += hv * hw[d * 3 + 2];
  }
  p0 = wave_sum(p0); p1 = wave_sum(p1); p2 = wave_sum(p2);
  if (lane == 0) {
    out[b * 3 + 0] = p0 + hb[0];
    out[b * 3 + 1] = p1 + hb[1];
    out[b * 3 + 2] = p2 + hb[2];
  }
}

extern "C" void kernel_launch(void* const* d_in, const int* in_sizes, int n_in,
                              void* d_out, int out_size, void* d_ws, size_t ws_size,
                              hipStream_t stream) {
  const float* x       = (const float*)d_in[0];
  const float* bin_l1  = (const float*)d_in[1];
  const float* bin_b1  = (const float*)d_in[2];
  const float* bin_l2  = (const float*)d_in[3];
  const float* bin_b2  = (const float*)d_in[4];
  const float* bin_y1  = (const float*)d_in[5];
  const float* bin_y2  = (const float*)d_in[6];
  const float* emb_w   = (const float*)d_in[7];
  const float* emb_b   = (const float*)d_in[8];
  const float* cls     = (const float*)d_in[9];
  const float* ln1_w   = (const float*)d_in[10];
  const float* ln1_b   = (const float*)d_in[11];
  const float* q_w     = (const float*)d_in[12];
  const float* k_w     = (const float*)d_in[13];
  const float* v_w     = (const float*)d_in[14];
  const float* g_w     = (const float*)d_in[15];
  const float* gk_w1   = (const float*)d_in[16];
  const float* gk_w2   = (const float*)d_in[17];
  const float* gk_b2   = (const float*)d_in[18];
  const float* gnorm_w = (const float*)d_in[19];
  const float* o_w     = (const float*)d_in[20];
  const float* ln2_w   = (const float*)d_in[21];
  const float* ln2_b   = (const float*)d_in[22];
  const float* mlp_w1  = (const float*)d_in[23];
  const float* mlp_b1  = (const float*)d_in[24];
  const float* mlp_w2  = (const float*)d_in[25];
  const float* mlp_b2  = (const float*)d_in[26];
  const float* head_w  = (const float*)d_in[27];
  const float* head_b  = (const float*)d_in[28];
  float* out = (float*)d_out;

  // ---- workspace layout (~193.5 MB) ----
  char* wptr = (char*)d_ws;
  auto alloc = [&](size_t bytes) { char* p = wptr; wptr += (bytes + 255) & ~(size_t)255; return p; };
  float* pos  = (float*)alloc((size_t)Tsz * Dsz * 4);
  float* h    = (float*)alloc((size_t)Mpad * Dsz * 4);
  short* xn   = (short*)alloc((size_t)Mpad * Dsz * 2);      // LN out; aliased as att
  float* qkvg = (float*)alloc((size_t)Mpad * QKVG * 4);     // packed q|k|v|g (also xbT, mid)
  float* gkeb = (float*)alloc((size_t)Mpad * DKsz * 4);
  float* gk1b = (float*)alloc((size_t)Mpad * 16 * 4);
  float* mt   = (float*)alloc((size_t)Bsz * Fsz * 4);
  float* rst  = (float*)alloc((size_t)Bsz * Fsz * 4);
  float* Ac   = (float*)alloc((size_t)Bsz * Hh * NCH * 32 * 4);
  float* Bc   = (float*)alloc((size_t)Bsz * Hh * NCH * 64 * 32 * 4);
  short* wtr  = (short*)alloc((size_t)3145728 * 2);         // per-layer bf16 weights
  float* xbT  = qkvg;            // [40][Mpad] fp32, dead before qkvg GEMM
  short* mid  = (short*)qkvg;    // MLP mid bf16, aliases qkvg (dead by MLP)
  short* att  = xn;              // scan output aliases xn (dead after gk1)

  short* qkvgT = wtr;                         // [1536][512]
  short* owT   = qkvgT + 786432;
  short* m1T   = owT + 262144;
  short* m2T   = m1T + 1048576;

  // ---- pre ----
  hipLaunchKernelGGL(pos_kernel, dim3((Tsz * Dsz + 255) / 256), dim3(256), 0, stream, pos);
  hipLaunchKernelGGL(tstat_kernel, dim3(Bsz * Fsz), dim3(64), 0, stream, x, mt, rst);
  hipLaunchKernelGGL(binorm_kernel, dim3(Mpad), dim3(64), 0, stream,
                     x, bin_l1, bin_b1, bin_l2, bin_b2, bin_y1, bin_y2, mt, rst, xbT);
  hipLaunchKernelGGL(embgemm_kernel, dim3(258, 8), dim3(256), 0, stream,
                     xbT, emb_w, emb_b, cls, pos, h);

  dim3 blk256(256);
  for (int l = 0; l < Lnum; ++l) {
    // per-layer weight convert (stream-ordered; wtr reused each layer)
    hipLaunchKernelGGL(wt4_kernel, dim3(16, 48), blk256, 0, stream,
                       q_w + (size_t)l*Dsz*DKsz, k_w + (size_t)l*Dsz*DKsz,
                       v_w + (size_t)l*Dsz*DVsz, g_w + (size_t)l*Dsz*DVsz, qkvgT);
    hipLaunchKernelGGL(wt_kernel, dim3(16, 16), blk256, 0, stream, o_w   + (size_t)l*DVsz*Dsz,  owT, DVsz, Dsz);
    hipLaunchKernelGGL(wt_kernel, dim3(16, 64), blk256, 0, stream, mlp_w1+ (size_t)l*Dsz*MLPsz, m1T, Dsz, MLPsz);
    hipLaunchKernelGGL(wt_kernel, dim3(64, 16), blk256, 0, stream, mlp_w2+ (size_t)l*MLPsz*Dsz, m2T, MLPsz, Dsz);

    const float* lw1 = ln1_w + l * Dsz;  const float* lb1 = ln1_b + l * Dsz;
    const float* g1w = gk_w1 + (size_t)l * Dsz * 16;
    const float* g2w = gk_w2 + (size_t)l * 16 * DKsz;
    const float* g2b = gk_b2 + (size_t)l * DKsz;
    const float* gnw = gnorm_w + l * HVsz;
    const float* lw2 = ln2_w + l * Dsz;  const float* lb2 = ln2_b + l * Dsz;
    const float* m1b = mlp_b1 + (size_t)l * MLPsz;
    const float* m2b = mlp_b2 + (size_t)l * Dsz;

    hipLaunchKernelGGL(ln_kernel, dim3(Msz), dim3(64), 0, stream, h, lw1, lb1, xn);

    // packed q|k|v|g projection (N=1536)
    hipLaunchKernelGGL((mgemm_kernel<0,0>), dim3(129, 12), blk256, 0, stream,
                       xn, qkvgT, (void*)qkvg, (const float*)nullptr, (const float*)nullptr, QKVG, Dsz);
    hipLaunchKernelGGL(gk1_kernel, dim3(Msz), dim3(64), 0, stream, xn, g1w, gk1b);
    hipLaunchKernelGGL(gk2_kernel, dim3(Msz), blk256, 0, stream, gk1b, g2w, g2b, gkeb);

    // chunk-parallel GLA scan
    hipLaunchKernelGGL(scanA_kernel, dim3(Bsz * Hh * NCH), dim3(64), 0, stream,
                       qkvg, gkeb, Ac, Bc);
    hipLaunchKernelGGL(scanB_kernel, dim3(Bsz * Hh), dim3(64), 0, stream, Ac, Bc);
    hipLaunchKernelGGL(scanC_kernel, dim3(Bsz * Hh * NCH), dim3(64), 0, stream,
                       qkvg, gkeb, gnw, Bc, att);

    // h = h + att @ o_w
    hipLaunchKernelGGL((mgemm_kernel<0,0>), dim3(129, 4), blk256, 0, stream,
                       att, owT, (void*)h, (const float*)nullptr, h, Dsz, DVsz);

    hipLaunchKernelGGL(ln_kernel, dim3(Msz), dim3(64), 0, stream, h, lw2, lb2, xn);
    // mid = gelu(xn @ w1 + b1)   (bf16 out)
    hipLaunchKernelGGL((mgemm_kernel<1,1>), dim3(129, 16), blk256, 0, stream,
                       xn, m1T, (void*)mid, m1b, (const float*)nullptr, MLPsz, Dsz);
    // h = h + mid @ w2 + b2
    hipLaunchKernelGGL((mgemm_kernel<0,0>), dim3(129, 4), blk256, 0, stream,
                       mid, m2T, (void*)h, m2b, h, Dsz, MLPsz);
  }

  hipLaunchKernelGGL(head_kernel, dim3(Bsz), dim3(64), 0, stream, h, head_w, head_b, out);
}

// Round 7
// 1805.031 us; speedup vs baseline: 4.4314x; 1.0006x over previous
//
#include <hip/hip_runtime.h>
#include <hip/hip_bf16.h>
#include <hip/hip_fp16.h>
#include <math.h>

// ---- problem constants ----
#define Bsz   32
#define Ssz   512
#define Fsz   40
#define Dsz   512
#define Hh    8
#define Lnum  4
#define Tsz   513           // S + 1 (cls token)
#define DKsz  256
#define DVsz  512
#define HKsz  32
#define HVsz  64
#define Msz   (Bsz*Tsz)     // 16416 rows
#define Mpad  16512         // 129*128, padded row count for 128-tiles
#define MLPsz 2048
#define NCH   16            // scan chunks per (b,h)
#define CSZ   33            // chunk size (last chunk = 18)
#define QKVG  1536          // packed q|k|v|g GEMM width
#define VOFF  8404992       // float offset of vP within qkP block (256*513*64)

typedef __attribute__((ext_vector_type(4))) float f32x4;
typedef __attribute__((ext_vector_type(8))) short bf16x8;

__device__ __forceinline__ float bf2f(short s) {
  unsigned int u = ((unsigned int)(unsigned short)s) << 16;
  return __builtin_bit_cast(float, u);
}
__device__ __forceinline__ short f2bf(float f) {
  __hip_bfloat16 b = __float2bfloat16(f);
  return __builtin_bit_cast(short, b);
}

__device__ __forceinline__ float wave_sum(float v) {
#pragma unroll
  for (int off = 32; off > 0; off >>= 1) v += __shfl_xor(v, off, 64);
  return v;
}

// ---- positional encoding table (T x D) ----
__global__ void pos_kernel(float* __restrict__ pos) {
  int idx = blockIdx.x * 256 + threadIdx.x;
  if (idx >= Tsz * Dsz) return;
  int t = idx / Dsz, d = idx % Dsz;
  float e = (float)(2 * (d >> 1)) / (float)Dsz;
  float den = powf(10000.f, e);
  float a = (float)t / den;
  pos[idx] = (d & 1) ? cosf(a) : sinf(a);
}

// ---- BiN temporal stats: per (b,f) mean + 1/std over S (ddof=1) ----
__global__ void tstat_kernel(const float* __restrict__ x,
                             float* __restrict__ mt, float* __restrict__ rst) {
  int bf = blockIdx.x;
  int b = bf / Fsz, f = bf % Fsz;
  int lane = threadIdx.x;
  const float* xp = x + (size_t)b * Ssz * Fsz + f;
  float s = 0.f, sq = 0.f;
  for (int i = lane; i < Ssz; i += 64) {
    float v = xp[(size_t)i * Fsz];
    s += v; sq += v * v;
  }
  s = wave_sum(s); sq = wave_sum(sq);
  if (lane == 0) {
    float m = s / (float)Ssz;
    float var = (sq - (float)Ssz * m * m) / (float)(Ssz - 1);
    float st = sqrtf(fmaxf(var, 0.f));
    if (st < 1e-4f) st = 1.f;
    mt[bf] = m;
    rst[bf] = 1.f / st;
  }
}

// ---- BiN both norms -> xbT[f][row] (transposed, fp32); zero cls/pad rows ----
__global__ __launch_bounds__(64) void binorm_kernel(
    const float* __restrict__ x, const float* __restrict__ l1,
    const float* __restrict__ b1, const float* __restrict__ l2,
    const float* __restrict__ b2, const float* __restrict__ y1p,
    const float* __restrict__ y2p, const float* __restrict__ mt,
    const float* __restrict__ rst, float* __restrict__ xbT) {
  int row = blockIdx.x;              // 0..Mpad-1
  int lane = threadIdx.x;
  int b = row / Tsz, t = row % Tsz;
  bool valid = (row < Msz) && (t < Ssz);
  if (!valid) {
    if (lane < Fsz) xbT[(size_t)lane * Mpad + row] = 0.f;
    return;
  }
  float xv = 0.f;
  const float* xp = x + ((size_t)b * Ssz + t) * Fsz;
  if (lane < Fsz) xv = xp[lane];
  float s  = wave_sum(lane < Fsz ? xv : 0.f);
  float sq = wave_sum(lane < Fsz ? xv * xv : 0.f);
  float m = s / (float)Fsz;
  float var = (sq - (float)Fsz * m * m) / (float)(Fsz - 1);
  float sf = sqrtf(fmaxf(var, 0.f));
  if (sf < 1e-4f) sf = 1.f;
  if (lane < Fsz) {
    float y1 = y1p[0], y2 = y2p[0];
    float z1 = (xv - m) / sf;
    float X1 = l1[t] * z1 + b1[t];
    int bf = b * Fsz + lane;
    float z2 = (xv - mt[bf]) * rst[bf];
    float X2 = l2[lane] * z2 + b2[lane];
    xbT[(size_t)lane * Mpad + row] = y1 * X1 + y2 * X2;
  }
}

// ---- embed GEMM: h[row][d] = xbT^T @ emb_w + emb_b + pos (cls rows special) ----
__global__ __launch_bounds__(256, 4) void embgemm_kernel(
    const float* __restrict__ xbT, const float* __restrict__ emb_w,
    const float* __restrict__ emb_b, const float* __restrict__ cls,
    const float* __restrict__ pos, float* __restrict__ h) {
  __shared__ float as[Fsz][64];
  __shared__ float bs[Fsz][64];
  int tid = threadIdx.x, tx = tid & 15, ty = tid >> 4;
  int r0 = blockIdx.x * 64, c0 = blockIdx.y * 64;
  for (int idx = tid; idx < Fsz * 64; idx += 256) {
    int f = idx >> 6, r = idx & 63;
    as[f][r] = xbT[(size_t)f * Mpad + r0 + r];
    bs[f][r] = emb_w[f * Dsz + c0 + r];
  }
  __syncthreads();
  float acc[4][4] = {};
#pragma unroll 5
  for (int f = 0; f < Fsz; ++f) {
    float4 a = *(const float4*)&as[f][ty * 4];
    float4 bv = *(const float4*)&bs[f][tx * 4];
    float av[4] = {a.x, a.y, a.z, a.w};
    float bw[4] = {bv.x, bv.y, bv.z, bv.w};
#pragma unroll
    for (int i = 0; i < 4; ++i)
#pragma unroll
      for (int j = 0; j < 4; ++j) acc[i][j] += av[i] * bw[j];
  }
#pragma unroll
  for (int i = 0; i < 4; ++i) {
    int gm = r0 + ty * 4 + i;
    int t = gm % Tsz;
    const float* pp = pos + (size_t)t * Dsz;
    bool iscls = (t == Ssz);
    int gn = c0 + tx * 4;
#pragma unroll
    for (int j = 0; j < 4; ++j) {
      float v = iscls ? (cls[gn + j] + pp[gn + j])
                      : (acc[i][j] + emb_b[gn + j] + pp[gn + j]);
      h[(size_t)gm * Dsz + gn + j] = v;
    }
  }
}

// ---- LayerNorm over D=512 (fp32 in, bf16 out) ----
__global__ __launch_bounds__(64) void ln_kernel(
    const float* __restrict__ in, const float* __restrict__ w,
    const float* __restrict__ b, short* __restrict__ out) {
  int row = blockIdx.x, lane = threadIdx.x;
  const float* p = in + (size_t)row * Dsz;
  float4 v0 = *(const float4*)(p + lane * 8);
  float4 v1 = *(const float4*)(p + lane * 8 + 4);
  float s  = v0.x + v0.y + v0.z + v0.w + v1.x + v1.y + v1.z + v1.w;
  float sq = v0.x*v0.x + v0.y*v0.y + v0.z*v0.z + v0.w*v0.w
           + v1.x*v1.x + v1.y*v1.y + v1.z*v1.z + v1.w*v1.w;
  s = wave_sum(s); sq = wave_sum(sq);
  float m = s * (1.f / Dsz);
  float var = sq * (1.f / Dsz) - m * m;
  float r = rsqrtf(var + 1e-5f);
  float4 w0 = *(const float4*)(w + lane * 8);
  float4 w1 = *(const float4*)(w + lane * 8 + 4);
  float4 b0 = *(const float4*)(b + lane * 8);
  float4 b1v = *(const float4*)(b + lane * 8 + 4);
  bf16x8 pk;
  pk[0] = f2bf((v0.x - m) * r * w0.x + b0.x);
  pk[1] = f2bf((v0.y - m) * r * w0.y + b0.y);
  pk[2] = f2bf((v0.z - m) * r * w0.z + b0.z);
  pk[3] = f2bf((v0.w - m) * r * w0.w + b0.w);
  pk[4] = f2bf((v1.x - m) * r * w1.x + b1v.x);
  pk[5] = f2bf((v1.y - m) * r * w1.y + b1v.y);
  pk[6] = f2bf((v1.z - m) * r * w1.z + b1v.z);
  pk[7] = f2bf((v1.w - m) * r * w1.w + b1v.w);
  *(bf16x8*)(out + (size_t)row * Dsz + lane * 8) = pk;
}

// ---- weight convert + transpose: Wt[n][k] = bf16(W[k][n]) ----
__global__ __launch_bounds__(256) void wt_kernel(const float* __restrict__ W,
    short* __restrict__ Wt, int K, int N) {
  __shared__ float t[32][33];
  int k0 = blockIdx.x * 32, n0 = blockIdx.y * 32;
  int tx = threadIdx.x & 31, ty = threadIdx.x >> 5;
#pragma unroll
  for (int r = 0; r < 32; r += 8)
    t[ty + r][tx] = W[(size_t)(k0 + ty + r) * N + n0 + tx];
  __syncthreads();
#pragma unroll
  for (int r = 0; r < 32; r += 8)
    Wt[(size_t)(n0 + ty + r) * K + k0 + tx] = f2bf(t[tx][ty + r]);
}

// ---- fused qkvg weight convert: Wt[1536][512] from 4 sources ----
__global__ __launch_bounds__(256) void wt4_kernel(const float* __restrict__ qw,
    const float* __restrict__ kw, const float* __restrict__ vw,
    const float* __restrict__ gw, short* __restrict__ Wt) {
  __shared__ float t[32][33];
  int k0 = blockIdx.x * 32, n0g = blockIdx.y * 32;
  const float* W; int n0, ld;
  if (n0g < 256)       { W = qw; n0 = n0g;        ld = DKsz; }
  else if (n0g < 512)  { W = kw; n0 = n0g - 256;  ld = DKsz; }
  else if (n0g < 1024) { W = vw; n0 = n0g - 512;  ld = DVsz; }
  else                 { W = gw; n0 = n0g - 1024; ld = DVsz; }
  int tx = threadIdx.x & 31, ty = threadIdx.x >> 5;
#pragma unroll
  for (int r = 0; r < 32; r += 8)
    t[ty + r][tx] = W[(size_t)(k0 + ty + r) * ld + n0 + tx];
  __syncthreads();
#pragma unroll
  for (int r = 0; r < 32; r += 8)
    Wt[(size_t)(n0g + ty + r) * Dsz + k0 + tx] = f2bf(t[tx][ty + r]);
}

// ---- bf16 MFMA GEMM, BK=64 ----
// SCAT 0: C[gm][gn] = act(..)+resid, OBF selects bf16/fp32 out.
// SCAT 1: qkvg scatter -> qkP (q|k per head), vP (=Cv+VOFF), gate fp16 -> resid ptr.
template<int ACT, int OBF, int SCAT>
__global__ __launch_bounds__(256) void mgemm_kernel(
    const short* __restrict__ A, const short* __restrict__ Bt,
    void* __restrict__ Cv, const float* __restrict__ bias,
    const float* __restrict__ resid, int N, int K) {
  __shared__ short As[128 * 64];
  __shared__ short Bs[128 * 64];
  int tid = threadIdx.x;
  int lane = tid & 63, wid = tid >> 6;
  int wr = wid >> 1, wc = wid & 1;
  int m0 = blockIdx.x * 128, n0 = blockIdx.y * 128;
  f32x4 acc[4][4];
#pragma unroll
  for (int i = 0; i < 4; ++i)
#pragma unroll
    for (int j = 0; j < 4; ++j) acc[i][j] = (f32x4){0.f, 0.f, 0.f, 0.f};

  int kq = lane >> 4;
  int rsel = lane & 15;

  for (int kt = 0; kt < K; kt += 64) {
#pragma unroll
    for (int i = 0; i < 4; ++i) {
      int li = i * 256 + tid;                 // granule 0..1023
      int row = li >> 3;
      int gsrc = (li & 7) ^ (row & 7);
      const short* ga = A + (size_t)(m0 + row) * K + kt + gsrc * 8;
      const short* gb = Bt + (size_t)(n0 + row) * K + kt + gsrc * 8;
      int base = (i * 256 + wid * 64) * 8;
      __builtin_amdgcn_global_load_lds(
          (const __attribute__((address_space(1))) unsigned int*)ga,
          (__attribute__((address_space(3))) unsigned int*)&As[base], 16, 0, 0);
      __builtin_amdgcn_global_load_lds(
          (const __attribute__((address_space(1))) unsigned int*)gb,
          (__attribute__((address_space(3))) unsigned int*)&Bs[base], 16, 0, 0);
    }
    __syncthreads();
#pragma unroll
    for (int s = 0; s < 2; ++s) {
      bf16x8 af[4], bfr[4];
#pragma unroll
      for (int i = 0; i < 4; ++i) {
        int row = wr * 64 + i * 16 + rsel;
        int slot = (s * 4 + kq) ^ (row & 7);
        af[i] = *(const bf16x8*)&As[row * 64 + slot * 8];
        int col = wc * 64 + i * 16 + rsel;
        int slotB = (s * 4 + kq) ^ (col & 7);
        bfr[i] = *(const bf16x8*)&Bs[col * 64 + slotB * 8];
      }
#pragma unroll
      for (int i = 0; i < 4; ++i)
#pragma unroll
        for (int j = 0; j < 4; ++j)
          acc[i][j] = __builtin_amdgcn_mfma_f32_16x16x32_bf16(af[i], bfr[j], acc[i][j], 0, 0, 0);
    }
    __syncthreads();
  }

#pragma unroll
  for (int i = 0; i < 4; ++i) {
    int rbase = m0 + wr * 64 + i * 16 + (lane >> 4) * 4;
#pragma unroll
    for (int j = 0; j < 4; ++j) {
      int gn = n0 + wc * 64 + j * 16 + (lane & 15);
      float bv = (SCAT == 0 && bias) ? bias[gn] : 0.f;
#pragma unroll
      for (int r = 0; r < 4; ++r) {
        int gm = rbase + r;
        float v = acc[i][j][r] + bv;
        if (SCAT == 0) {
          if (ACT == 1) v = 0.5f * v * (1.f + erff(v * 0.70710678118654752f));
          if (resid) v += resid[(size_t)gm * N + gn];
          if (OBF) ((short*)Cv)[(size_t)gm * N + gn] = f2bf(v);
          else     ((float*)Cv)[(size_t)gm * N + gn] = v;
        } else {
          if (gm < Msz) {
            int bq = gm / Tsz, tq = gm - bq * Tsz;
            if (gn < 512) {                      // q | k
              int hq = (gn >> 5) & 7;
              int off = (gn & 31) | ((gn & 256) >> 3);
              ((float*)Cv)[(((size_t)bq * 8 + hq) * Tsz + tq) * 64 + off] = v;
            } else if (gn < 1024) {              // v
              int hq = (gn >> 6) & 7;
              ((float*)Cv)[(size_t)VOFF + (((size_t)bq * 8 + hq) * Tsz + tq) * 64 + (gn & 63)] = v;
            } else {                             // gate -> fp16 (10-bit mantissa)
              int hq = (gn >> 6) & 7;
              ((__half*)const_cast<float*>(resid))[(((size_t)bq * 8 + hq) * Tsz + tq) * 64 + (gn & 63)] = __float2half(v);
            }
          }
        }
      }
    }
  }
}

// ---- gk low-rank part 1: gk1[m,16] = xn[m,:] @ w1 (bf16 in, fp32 out) ----
__global__ __launch_bounds__(64) void gk1_kernel(const short* __restrict__ xn,
    const float* __restrict__ w1, float* __restrict__ gk1) {
  int m = blockIdx.x, lane = threadIdx.x;
  __shared__ float xr[512];
  bf16x8 v = *(const bf16x8*)(xn + (size_t)m * Dsz + lane * 8);
#pragma unroll
  for (int e = 0; e < 8; ++e) xr[lane * 8 + e] = bf2f(v[e]);
  __syncthreads();
  int c = lane & 15, q = lane >> 4;
  float acc = 0.f;
#pragma unroll 8
  for (int i = 0; i < 128; ++i) {
    int k = q * 128 + i;
    acc += xr[k] * w1[k * 16 + c];
  }
  acc += __shfl_xor(acc, 16, 64);
  acc += __shfl_xor(acc, 32, 64);
  if (lane < 16) gk1[(size_t)m * 16 + c] = acc;
}

// ---- gk part 2: gkeP[bh][t][32] = exp(log_sigmoid(gk1 @ w2 + b2)/16) ----
__global__ __launch_bounds__(256) void gk2_kernel(
    const float* __restrict__ gk1, const float* __restrict__ w2,
    const float* __restrict__ b2, float* __restrict__ gkeP) {
  int m = blockIdx.x, n = threadIdx.x;
  __shared__ float row[16];
  if (n < 16) row[n] = gk1[(size_t)m * 16 + n];
  __syncthreads();
  float acc = b2[n];
#pragma unroll
  for (int kk = 0; kk < 16; ++kk) acc += row[kk] * w2[kk * 256 + n];
  float z = acc;
  float ls = (z >= 0.f) ? -log1pf(expf(-z)) : z - log1pf(expf(z));
  int b = m / Tsz, t = m - b * Tsz;
  int h = n >> 5;
  gkeP[(((size_t)b * 8 + h) * Tsz + t) * 32 + (n & 31)] = expf(ls * 0.0625f);
}

// ---- scan A: LDS-staged chunk-local scan from S=0 -> Ac, Bc ----
__global__ __launch_bounds__(64) void scanA_kernel(
    const float* __restrict__ qkP, const float* __restrict__ gkeP,
    float* __restrict__ Ac, float* __restrict__ Bc) {
  int gid = blockIdx.x;            // bh*NCH + c
  int bh = gid >> 4, c = gid & 15;
  int lane = threadIdx.x;
  int t0 = c * CSZ;
  int nst = min(CSZ, Tsz - t0);
  __shared__ __align__(16) float s_k[CSZ * 32];
  __shared__ __align__(16) float s_g[CSZ * 32];
  __shared__ __align__(16) float s_v[CSZ * 64];
  const size_t rowbase = (size_t)bh * Tsz + t0;
  const float* qksrc = qkP + rowbase * 64;
  const float* vsrc  = qkP + (size_t)VOFF + rowbase * 64;
  const float* gsrc  = gkeP + rowbase * 32;
  int nkg = nst * 8;               // 128B/step granules
#pragma unroll
  for (int i = 0; i < 5; ++i) {
    int gi = i * 64 + lane;
    if (gi < nkg) {
      int st = gi >> 3, g4 = (gi & 7) * 4;
      __builtin_amdgcn_global_load_lds(
        (const __attribute__((address_space(1))) unsigned int*)(qksrc + (size_t)st * 64 + 32 + g4),
        (__attribute__((address_space(3))) unsigned int*)s_k + i * 256, 16, 0, 0);
      __builtin_amdgcn_global_load_lds(
        (const __attribute__((address_space(1))) unsigned int*)(gsrc + (size_t)gi * 4),
        (__attribute__((address_space(3))) unsigned int*)s_g + i * 256, 16, 0, 0);
    }
  }
  int nv = nst * 16;
#pragma unroll
  for (int i = 0; i < 9; ++i) {
    int gi = i * 64 + lane;
    if (gi < nv)
      __builtin_amdgcn_global_load_lds(
        (const __attribute__((address_space(1))) unsigned int*)(vsrc + (size_t)gi * 4),
        (__attribute__((address_space(3))) unsigned int*)s_v + i * 256, 16, 0, 0);
  }
  float S[32];
#pragma unroll
  for (int i = 0; i < 32; ++i) S[i] = 0.f;
  float ac = 1.f;
  __syncthreads();
  for (int ts = 0; ts < nst; ++ts) {
    float vv = s_v[ts * 64 + lane];
#pragma unroll
    for (int j = 0; j < 8; ++j) {
      float4 kk = *(const float4*)&s_k[ts * 32 + j * 4];
      float4 gg = *(const float4*)&s_g[ts * 32 + j * 4];
      S[4*j+0] = S[4*j+0] * gg.x + kk.x * vv;
      S[4*j+1] = S[4*j+1] * gg.y + kk.y * vv;
      S[4*j+2] = S[4*j+2] * gg.z + kk.z * vv;
      S[4*j+3] = S[4*j+3] * gg.w + kk.w * vv;
    }
    ac *= s_g[ts * 32 + (lane & 31)];
  }
  float* bp = Bc + ((size_t)gid * 64 + lane) * 32;
#pragma unroll
  for (int j = 0; j < 8; ++j)
    *(float4*)(bp + j * 4) = make_float4(S[4*j+0], S[4*j+1], S[4*j+2], S[4*j+3]);
  if (lane < 32) Ac[(size_t)gid * 32 + lane] = ac;
}

// ---- scan B: per (b,h) combine chunks; Bc slot c := S_init(c) (in place) ----
__global__ __launch_bounds__(64) void scanB_kernel(
    const float* __restrict__ Ac, float* __restrict__ Bc) {
  int bh = blockIdx.x;
  int lane = threadIdx.x;
  float cur[32];
#pragma unroll
  for (int i = 0; i < 32; ++i) cur[i] = 0.f;
  __shared__ float sA[32];
  for (int c = 0; c < NCH; ++c) {
    size_t gid = (size_t)bh * NCH + c;
    float* bp = Bc + (gid * 64 + lane) * 32;
    __syncthreads();
    if (lane < 32) sA[lane] = Ac[gid * 32 + lane];
    __syncthreads();
    float4 tb[8];
#pragma unroll
    for (int j = 0; j < 8; ++j) tb[j] = *(const float4*)(bp + j * 4);
#pragma unroll
    for (int j = 0; j < 8; ++j)
      *(float4*)(bp + j * 4) = make_float4(cur[4*j+0], cur[4*j+1], cur[4*j+2], cur[4*j+3]);
#pragma unroll
    for (int j = 0; j < 8; ++j) {
      cur[4*j+0] = sA[4*j+0] * cur[4*j+0] + tb[j].x;
      cur[4*j+1] = sA[4*j+1] * cur[4*j+1] + tb[j].y;
      cur[4*j+2] = sA[4*j+2] * cur[4*j+2] + tb[j].z;
      cur[4*j+3] = sA[4*j+3] * cur[4*j+3] + tb[j].w;
    }
  }
}

// ---- scan C: LDS-staged re-scan from S_init, emit att (bf16) ----
__global__ __launch_bounds__(64) void scanC_kernel(
    const float* __restrict__ qkP, const __half* __restrict__ gP,
    const float* __restrict__ gkeP, const float* __restrict__ gnw,
    const float* __restrict__ Bc, short* __restrict__ att) {
  int gid = blockIdx.x;
  int bh = gid >> 4, c = gid & 15;
  int b = bh >> 3, hh = bh & 7;
  int lane = threadIdx.x;
  int t0 = c * CSZ;
  int nst = min(CSZ, Tsz - t0);
  __shared__ __align__(16) float s_qk[CSZ * 64];
  __shared__ __align__(16) float s_g[CSZ * 32];
  __shared__ __align__(16) float s_v[CSZ * 64];
  __shared__ __align__(16) __half s_gt[CSZ * 64];
  const size_t rowbase = (size_t)bh * Tsz + t0;
  const float* qksrc = qkP + rowbase * 64;
  const float* vsrc  = qkP + (size_t)VOFF + rowbase * 64;
  const float* gsrc  = gkeP + rowbase * 32;
  const __half* gtsrc = gP + rowbase * 64;
  int n16 = nst * 16;
#pragma unroll
  for (int i = 0; i < 9; ++i) {
    int gi = i * 64 + lane;
    if (gi < n16) {
      __builtin_amdgcn_global_load_lds(
        (const __attribute__((address_space(1))) unsigned int*)(qksrc + (size_t)gi * 4),
        (__attribute__((address_space(3))) unsigned int*)s_qk + i * 256, 16, 0, 0);
      __builtin_amdgcn_global_load_lds(
        (const __attribute__((address_space(1))) unsigned int*)(vsrc + (size_t)gi * 4),
        (__attribute__((address_space(3))) unsigned int*)s_v + i * 256, 16, 0, 0);
    }
  }
  int n8 = nst * 8;
#pragma unroll
  for (int i = 0; i < 5; ++i) {
    int gi = i * 64 + lane;
    if (gi < n8) {
      __builtin_amdgcn_global_load_lds(
        (const __attribute__((address_space(1))) unsigned int*)(gsrc + (size_t)gi * 4),
        (__attribute__((address_space(3))) unsigned int*)s_g + i * 256, 16, 0, 0);
      __builtin_amdgcn_global_load_lds(
        (const __attribute__((address_space(1))) unsigned int*)((const unsigned int*)gtsrc + (size_t)gi * 4),
        (__attribute__((address_space(3))) unsigned int*)s_gt + i * 256, 16, 0, 0);
    }
  }
  float S[32];
  const float* sp = Bc + ((size_t)gid * 64 + lane) * 32;
#pragma unroll
  for (int j = 0; j < 8; ++j) {
    float4 sv4 = *(const float4*)(sp + j * 4);
    S[4*j+0] = sv4.x; S[4*j+1] = sv4.y; S[4*j+2] = sv4.z; S[4*j+3] = sv4.w;
  }
  float gn = gnw[lane];
  __syncthreads();
  for (int ts = 0; ts < nst; ++ts) {
    float vv = s_v[ts * 64 + lane];
    float gv = __half2float(s_gt[ts * 64 + lane]);
    float o = 0.f;
#pragma unroll
    for (int j = 0; j < 8; ++j) {
      float4 qq = *(const float4*)&s_qk[ts * 64 + j * 4];
      float4 kk = *(const float4*)&s_qk[ts * 64 + 32 + j * 4];
      float4 gg = *(const float4*)&s_g[ts * 32 + j * 4];
      S[4*j+0] = S[4*j+0] * gg.x + kk.x * vv;  o += qq.x * S[4*j+0];
      S[4*j+1] = S[4*j+1] * gg.y + kk.y * vv;  o += qq.y * S[4*j+1];
      S[4*j+2] = S[4*j+2] * gg.z + kk.z * vv;  o += qq.z * S[4*j+2];
      S[4*j+3] = S[4*j+3] * gg.w + kk.w * vv;  o += qq.w * S[4*j+3];
    }
    o *= 0.17677669529663689f;   // 32^-0.5
    float ss = wave_sum(o * o);
    float r = rsqrtf(ss * (1.f / 64.f) + 1e-5f);
    float sig = 1.f / (1.f + expf(-gv));
    att[((size_t)b * Tsz + t0 + ts) * DVsz + hh * HVsz + lane] = f2bf(o * r * gn * gv * sig);
  }
}

// ---- final head ----
__global__ __launch_bounds__(64) void head_kernel(
    const float* __restrict__ h, const float* __restrict__ hw,
    const float* __restrict__ hb, float* __restrict__ out) {
  int b = blockIdx.x, lane = threadIdx.x;
  const float* p = h + ((size_t)b * Tsz + Ssz) * Dsz;
  float p0 = 0.f, p1 = 0.f, p2 = 0.f;
#pragma unroll
  for (int j = 0; j < 8; ++j) {
    int d = lane + j * 64;
    float hv = p[d];
    p0 += hv * hw[d * 3 + 0];
    p1 += hv * hw[d * 3 + 1];
    p2 += hv * hw[d * 3 + 2];
  }
  p0 = wave_sum(p0); p1 = wave_sum(p1); p2 = wave_sum(p2);
  if (lane == 0) {
    out[b * 3 + 0] = p0 + hb[0];
    out[b * 3 + 1] = p1 + hb[1];
    out[b * 3 + 2] = p2 + hb[2];
  }
}

extern "C" void kernel_launch(void* const* d_in, const int* in_sizes, int n_in,
                              void* d_out, int out_size, void* d_ws, size_t ws_size,
                              hipStream_t stream) {
  const float* x       = (const float*)d_in[0];
  const float* bin_l1  = (const float*)d_in[1];
  const float* bin_b1  = (const float*)d_in[2];
  const float* bin_l2  = (const float*)d_in[3];
  const float* bin_b2  = (const float*)d_in[4];
  const float* bin_y1  = (const float*)d_in[5];
  const float* bin_y2  = (const float*)d_in[6];
  const float* emb_w   = (const float*)d_in[7];
  const float* emb_b   = (const float*)d_in[8];
  const float* cls     = (const float*)d_in[9];
  const float* ln1_w   = (const float*)d_in[10];
  const float* ln1_b   = (const float*)d_in[11];
  const float* q_w     = (const float*)d_in[12];
  const float* k_w     = (const float*)d_in[13];
  const float* v_w     = (const float*)d_in[14];
  const float* g_w     = (const float*)d_in[15];
  const float* gk_w1   = (const float*)d_in[16];
  const float* gk_w2   = (const float*)d_in[17];
  const float* gk_b2   = (const float*)d_in[18];
  const float* gnorm_w = (const float*)d_in[19];
  const float* o_w     = (const float*)d_in[20];
  const float* ln2_w   = (const float*)d_in[21];
  const float* ln2_b   = (const float*)d_in[22];
  const float* mlp_w1  = (const float*)d_in[23];
  const float* mlp_b1  = (const float*)d_in[24];
  const float* mlp_w2  = (const float*)d_in[25];
  const float* mlp_b2  = (const float*)d_in[26];
  const float* head_w  = (const float*)d_in[27];
  const float* head_b  = (const float*)d_in[28];
  float* out = (float*)d_out;

  // ---- workspace layout (~194.5 MB, same as proven R6 allocation) ----
  char* wptr = (char*)d_ws;
  auto alloc = [&](size_t bytes) { char* p = wptr; wptr += (bytes + 255) & ~(size_t)255; return p; };
  float* pos  = (float*)alloc((size_t)Tsz * Dsz * 4);
  float* h    = (float*)alloc((size_t)Mpad * Dsz * 4);
  short* xn   = (short*)alloc((size_t)Mpad * Dsz * 2);      // LN out; aliased as att
  float* qkP  = (float*)alloc((size_t)Mpad * MLPsz * 2);    // qkP|vP packed; also xbT / mid
  float* gkeP = (float*)alloc((size_t)256 * Tsz * 32 * 4);
  __half* gP  = (__half*)alloc((size_t)256 * Tsz * 64 * 2);
  float* gk1b = (float*)alloc((size_t)Mpad * 16 * 4);
  float* mt   = (float*)alloc((size_t)Bsz * Fsz * 4);
  float* rst  = (float*)alloc((size_t)Bsz * Fsz * 4);
  float* Ac   = (float*)alloc((size_t)Bsz * Hh * NCH * 32 * 4);
  float* Bc   = (float*)alloc((size_t)Bsz * Hh * NCH * 64 * 32 * 4);
  short* wtr  = (short*)alloc((size_t)3145728 * 2);         // per-layer bf16 weights
  float* xbT  = qkP;             // [40][Mpad] fp32, dead before qkv GEMM
  short* mid  = (short*)qkP;     // MLP mid bf16, aliases qkP/vP (dead by MLP)
  short* att  = xn;              // scan output aliases xn (dead after gk1)

  short* qkvT = wtr;                          // [1536][512]
  short* owT  = qkvT + 786432;
  short* m1T  = owT + 262144;
  short* m2T  = m1T + 1048576;

  // ---- pre ----
  hipLaunchKernelGGL(pos_kernel, dim3((Tsz * Dsz + 255) / 256), dim3(256), 0, stream, pos);
  hipLaunchKernelGGL(tstat_kernel, dim3(Bsz * Fsz), dim3(64), 0, stream, x, mt, rst);
  hipLaunchKernelGGL(binorm_kernel, dim3(Mpad), dim3(64), 0, stream,
                     x, bin_l1, bin_b1, bin_l2, bin_b2, bin_y1, bin_y2, mt, rst, xbT);
  hipLaunchKernelGGL(embgemm_kernel, dim3(258, 8), dim3(256), 0, stream,
                     xbT, emb_w, emb_b, cls, pos, h);

  dim3 blk256(256);
  for (int l = 0; l < Lnum; ++l) {
    hipLaunchKernelGGL(wt4_kernel, dim3(16, 48), blk256, 0, stream,
                       q_w + (size_t)l*Dsz*DKsz, k_w + (size_t)l*Dsz*DKsz,
                       v_w + (size_t)l*Dsz*DVsz, g_w + (size_t)l*Dsz*DVsz, qkvT);
    hipLaunchKernelGGL(wt_kernel, dim3(16, 16), blk256, 0, stream, o_w   + (size_t)l*DVsz*Dsz,  owT, DVsz, Dsz);
    hipLaunchKernelGGL(wt_kernel, dim3(16, 64), blk256, 0, stream, mlp_w1+ (size_t)l*Dsz*MLPsz, m1T, Dsz, MLPsz);
    hipLaunchKernelGGL(wt_kernel, dim3(64, 16), blk256, 0, stream, mlp_w2+ (size_t)l*MLPsz*Dsz, m2T, MLPsz, Dsz);

    const float* lw1 = ln1_w + l * Dsz;  const float* lb1 = ln1_b + l * Dsz;
    const float* g1w = gk_w1 + (size_t)l * Dsz * 16;
    const float* g2w = gk_w2 + (size_t)l * 16 * DKsz;
    const float* g2b = gk_b2 + (size_t)l * DKsz;
    const float* gnw = gnorm_w + l * HVsz;
    const float* lw2 = ln2_w + l * Dsz;  const float* lb2 = ln2_b + l * Dsz;
    const float* m1b = mlp_b1 + (size_t)l * MLPsz;
    const float* m2b = mlp_b2 + (size_t)l * Dsz;

    hipLaunchKernelGGL(ln_kernel, dim3(Msz), dim3(64), 0, stream, h, lw1, lb1, xn);

    // packed q|k|v|g projection (N=1536) with scatter epilogue
    hipLaunchKernelGGL((mgemm_kernel<0,0,1>), dim3(129, 12), blk256, 0, stream,
                       xn, qkvT, (void*)qkP, (const float*)nullptr, (const float*)gP, QKVG, Dsz);
    hipLaunchKernelGGL(gk1_kernel, dim3(Msz), dim3(64), 0, stream, xn, g1w, gk1b);
    hipLaunchKernelGGL(gk2_kernel, dim3(Msz), blk256, 0, stream, gk1b, g2w, g2b, gkeP);

    // chunk-parallel GLA scan (LDS-staged)
    hipLaunchKernelGGL(scanA_kernel, dim3(Bsz * Hh * NCH), dim3(64), 0, stream,
                       qkP, gkeP, Ac, Bc);
    hipLaunchKernelGGL(scanB_kernel, dim3(Bsz * Hh), dim3(64), 0, stream, Ac, Bc);
    hipLaunchKernelGGL(scanC_kernel, dim3(Bsz * Hh * NCH), dim3(64), 0, stream,
                       qkP, gP, gkeP, gnw, Bc, att);

    // h = h + att @ o_w
    hipLaunchKernelGGL((mgemm_kernel<0,0,0>), dim3(129, 4), blk256, 0, stream,
                       att, owT, (void*)h, (const float*)nullptr, h, Dsz, DVsz);

    hipLaunchKernelGGL(ln_kernel, dim3(Msz), dim3(64), 0, stream, h, lw2, lb2, xn);
    // mid = gelu(xn @ w1 + b1)   (bf16 out)
    hipLaunchKernelGGL((mgemm_kernel<1,1,0>), dim3(129, 16), blk256, 0, stream,
                       xn, m1T, (void*)mid, m1b, (const float*)nullptr, MLPsz, Dsz);
    // h = h + mid @ w2 + b2
    hipLaunchKernelGGL((mgemm_kernel<0,0,0>), dim3(129, 4), blk256, 0, stream,
                       mid, m2T, (void*)h, m2b, h, Dsz, MLPsz);
  }

  hipLaunchKernelGGL(head_kernel, dim3(Bsz), dim3(64), 0, stream, h, head_w, head_b, out);
}